// Round 11
// baseline (10860.785 us; speedup 1.0000x reference)
//
#include <hip/hip_runtime.h>
#include <hip/hip_bf16.h>
#include <cstdint>
#include <cstddef>

constexpr int BATCH = 64;
constexpr int SEQ   = 512;
constexpr int DIM   = 256;
constexpr int HID   = 1024;
constexpr int COUT  = 128;
constexpr int KTOT  = DIM + HID;   // 1280
constexpr int NGATE = 4 * HID;     // 4096
constexpr float ATT_SIG_W = 3.0f;

using bf16x8 = __attribute__((ext_vector_type(8))) __bf16;
using f32x4  = __attribute__((ext_vector_type(4))) float;
using u32x4  = __attribute__((ext_vector_type(4))) unsigned int;

__device__ __forceinline__ unsigned short f2bf(float f) {
    union { float f; unsigned u; } v; v.f = f;
    unsigned u = v.u;
    u += 0x7fffu + ((u >> 16) & 1u);
    return (unsigned short)(u >> 16);
}

__device__ __forceinline__ float sigm(float x) { return 1.f / (1.f + __expf(-x)); }

// 16B write-through store (sc0 sc1); payload must be ext_vector_type (reg quad)
__device__ __forceinline__ void store_16B_wt(void* p, u32x4 v) {
    asm volatile("global_store_dwordx4 %0, %1, off sc0 sc1"
                 :: "v"(p), "v"(v) : "memory");
}

// global->LDS direct copy, 16B/lane, NORMAL CACHING (aux=0): L2 serves the
// 32-CU/XCD broadcast (vs R10's sc0sc1 bypass = 32x fabric traffic).
// Coherence: producers write h via WT (sc0 sc1) so L3 is always current; the
// per-step acquire fence (buffer_inv) below drops stale clean L2/L1 lines.
#define GLOAD_LDS_CACHED(gptr, lptr)                                       \
    __builtin_amdgcn_global_load_lds(                                      \
        (const __attribute__((address_space(1))) void*)(gptr),             \
        (__attribute__((address_space(3))) void*)(lptr), 16, 0, 0)

// ---- weight transpose+convert: out[n][k] = bf16( k<DIM ? wi[k][n] : wh[k-DIM][n] )
__global__ void transpose_weights(const float* __restrict__ wi,
                                  const float* __restrict__ wh,
                                  unsigned short* __restrict__ out, int N) {
    __shared__ float tile[64][65];
    int ntiles = N >> 6;
    int kt = blockIdx.x / ntiles;
    int nt = blockIdx.x % ntiles;
    int k0 = kt << 6, n0 = nt << 6;
    int a = threadIdx.x & 63, g = threadIdx.x >> 6;
#pragma unroll
    for (int p = 0; p < 16; ++p) {
        int kr = p * 4 + g;
        int k = k0 + kr;
        const float* src = (k < DIM) ? (wi + (size_t)k * N) : (wh + (size_t)(k - DIM) * N);
        tile[kr][a] = src[n0 + a];
    }
    __syncthreads();
#pragma unroll
    for (int p = 0; p < 16; ++p) {
        int nr = p * 4 + g;
        out[(size_t)(n0 + nr) * KTOT + (k0 + a)] = f2bf(tile[a][nr]);
    }
}

// ---- x [B][T][D] f32 -> xt [T][B][D] bf16
__global__ void transpose_x(const float* __restrict__ x, unsigned short* __restrict__ xt) {
    size_t idx = (size_t)blockIdx.x * blockDim.x + threadIdx.x;
    if (idx >= (size_t)SEQ * BATCH * DIM) return;
    int d = idx % DIM;
    size_t r = idx / DIM;
    int b = r % BATCH;
    int t = r / BATCH;
    xt[idx] = f2bf(x[((size_t)b * SEQ + t) * DIM + d]);
}

// ---- pack LSTM weights into per-(colgroup, khalf) MFMA fragment order.
__global__ void pack_lstm(const unsigned short* __restrict__ WT,
                          unsigned short* __restrict__ out) {
    int cg = blockIdx.x >> 1, kh = blockIdx.x & 1;
    size_t base = (size_t)blockIdx.x * 20480;
#pragma unroll
    for (int j = 0; j < 80; ++j) {
        int idx = threadIdx.x * 80 + j;
        int frag = idx >> 9;
        int rem = idx & 511;
        int lane = rem >> 3, e = rem & 7;
        int nt = frag / 20, ksl = frag % 20;
        int p = nt * 16 + (lane & 15);
        int origcol = (p >> 3) * 1024 + cg * 8 + (p & 7);
        int k = kh * 640 + ksl * 32 + ((lane >> 4) & 3) * 8 + e;
        out[base + idx] = WT[(size_t)origcol * KTOT + k];
    }
}

// ---- pack TAGM weights: region (cg,kh): 20 frags x 1024B; col = cg*16+(lane&15)
__global__ void pack_tagm(const unsigned short* __restrict__ WT,
                          unsigned short* __restrict__ out) {
    int cg = blockIdx.x >> 1, kh = blockIdx.x & 1;
    size_t base = (size_t)blockIdx.x * 10240;
#pragma unroll
    for (int j = 0; j < 40; ++j) {
        int idx = threadIdx.x * 40 + j;
        int ksl = idx >> 9;
        int rem = idx & 511;
        int lane = rem >> 3, e = rem & 7;
        int origcol = cg * 16 + (lane & 15);
        int k = kh * 640 + ksl * 32 + ((lane >> 4) & 3) * 8 + e;
        out[base + idx] = WT[(size_t)origcol * KTOT + k];
    }
}

// ---- per-step barrier: producers use WT stores (no release fence needed);
// acquire fence (buffer_inv, cheap: no dirty lines) after poll so the cached
// stage reads see the coherent L3 image.
__device__ __forceinline__ void flag_light(unsigned* flags, int base, int cnt,
                                           int myidx, unsigned epoch) {
    asm volatile("s_waitcnt vmcnt(0)" ::: "memory");  // drain own WT stores
    __syncthreads();
    if (threadIdx.x == 0)
        __hip_atomic_store(flags + myidx, epoch, __ATOMIC_RELAXED, __HIP_MEMORY_SCOPE_AGENT);
    if (threadIdx.x < 64) {
        for (;;) {
            bool ok = true;
            for (int j = (int)threadIdx.x; j < cnt; j += 64)
                ok &= (__hip_atomic_load(flags + base + j, __ATOMIC_RELAXED,
                                         __HIP_MEMORY_SCOPE_AGENT) >= epoch);
            if (__all(ok)) break;
            __builtin_amdgcn_s_sleep(1);
        }
        if (threadIdx.x == 0)
            __builtin_amdgcn_fence(__ATOMIC_ACQUIRE, "agent");   // inv: L1+L2 stale lines
    }
    __syncthreads();
}

// ---- HEAVY barrier (phase boundaries only): full release/acquire fences
__device__ __forceinline__ void flag_barrier(unsigned* flags, int base, int cnt,
                                             int myidx, unsigned epoch) {
    __syncthreads();
    if (threadIdx.x == 0) {
        __builtin_amdgcn_fence(__ATOMIC_RELEASE, "agent");   // wbl2
        __hip_atomic_store(flags + myidx, epoch, __ATOMIC_RELAXED, __HIP_MEMORY_SCOPE_AGENT);
    }
    if (threadIdx.x < 64) {
        for (;;) {
            bool ok = true;
            for (int j = (int)threadIdx.x; j < cnt; j += 64)
                ok &= (__hip_atomic_load(flags + base + j, __ATOMIC_RELAXED,
                                         __HIP_MEMORY_SCOPE_AGENT) >= epoch);
            if (__all(ok)) break;
            __builtin_amdgcn_s_sleep(1);
        }
        if (threadIdx.x == 0)
            __builtin_amdgcn_fence(__ATOMIC_ACQUIRE, "agent");   // inv
    }
    __syncthreads();
}

// ======== persistent fused kernel ========
// grid 256 x 256thr (VGPR ~208, no spill). h global layout BLOCKED:
// chunk s = cg8*64 + row (cg8 = h_col>>3), 16B/chunk; stage = identity linear
// copy THROUGH L2 (XCD L2 serves the 32-CU broadcast); h writes = LDS transpose
// scratch -> 16B full-line WT stores; att_part also WT (per-step inv safety).
// LSTM: block = (dir = bid&1, cg = bid>>1 : 8 h-cols x 4 gates). wave = (mh, kh).
// TAGM (bid<64): 16 h-cols/block.
__global__ __launch_bounds__(256)
void tagm_fused(const unsigned short* __restrict__ xt,
                const unsigned short* __restrict__ Wfp,
                const unsigned short* __restrict__ Wbp,
                const unsigned short* __restrict__ Wtp,
                const float* __restrict__ bias_f, const float* __restrict__ bias_b,
                const float* __restrict__ attw, const float* __restrict__ att_fc_b,
                const float* __restrict__ i2h_b, const float* __restrict__ h2h_b,
                const float* __restrict__ fc_w, const float* __restrict__ fc_b,
                unsigned short* __restrict__ h_lstm,  // [2 dir][2 buf] x 128KB blocked
                unsigned short* __restrict__ h_tagm,  // [2 buf] x 128KB blocked
                float* __restrict__ h_f32,            // [64][1024]
                float* __restrict__ att_part,         // [256 blk][512*64] f32 (aliases Wfp/Wbp!)
                unsigned* __restrict__ flags,         // [640]
                float* __restrict__ out) {
    extern __shared__ char smem[];                   // [0,131072): blocked h image
    char* dumpbase = smem + 131072;                  // 8 KB acc dump
    float* auxf = (float*)(smem + 131072 + 8192);    // 4 KB: LSTM c / TAGM h master
    unsigned short* hscr = (unsigned short*)(smem + 131072 + 8192 + 4096);  // 2 KB

    int tid = threadIdx.x;
    int wave = tid >> 6, lane = tid & 63;
    int bid = blockIdx.x;
    int dir = bid & 1, cg = bid >> 1;
    int mh = wave >> 1, kh = wave & 1;
    int q = lane >> 4, c15 = lane & 15;

    // ---- LSTM weight fragments -> registers
    bf16x8 wreg[40];
    {
        const unsigned short* wp = (dir ? Wbp : Wfp) + (size_t)(cg * 2 + kh) * 20480;
#pragma unroll
        for (int f = 0; f < 40; ++f)
            wreg[f] = *(const bf16x8*)(wp + f * 512 + lane * 8);
    }
    int hc = lane & 7;
    int colE = cg * 8 + hc;
    const float* bias = dir ? bias_b : bias_f;
    float b_ii = bias[colE], b_ff = bias[HID + colE];
    float b_gg = bias[2 * HID + colE], b_oo = bias[3 * HID + colE];
    float attw_l = attw[dir * HID + colE];

    for (int i = tid; i < 512; i += 256) auxf[i] = 0.f;   // c = 0

    // weights in regs (vmcnt-drained by flag_light) before att_part clobbers Wfp/Wbp
    flag_light(flags, 256, 256, 256 + bid, 1u);

    // =============== LSTM loop ===============
    for (int t = 0; t < SEQ; ++t) {
        int tx = dir ? (SEQ - 1 - t) : t;
        {   // stage h_prev -> LDS: identity linear copy of blocked image, via L2
            const char* hsrc = (const char*)h_lstm + (size_t)(dir * 2 + (t & 1)) * 131072;
            char* lbase = smem + (size_t)(tid & 192) * 16;
#pragma unroll
            for (int i = 0; i < 32; ++i) {
                int s = i * 256 + tid;                 // chunk index == LDS chunk index
                GLOAD_LDS_CACHED(hsrc + (size_t)s * 16, lbase + (size_t)i * 4096);
            }
        }
        // prefetch x fragments (normal cached loads; xt read-only, L2-resident)
        const unsigned short* xrow = xt + (size_t)tx * BATCH * DIM;
        bf16x8 xa[16];
        if (kh == 0) {
#pragma unroll
            for (int ksl = 0; ksl < 8; ++ksl)
#pragma unroll
                for (int mt = 0; mt < 2; ++mt) {
                    int row = mh * 32 + mt * 16 + c15;
                    xa[ksl * 2 + mt] = *(const bf16x8*)(xrow + row * DIM + ksl * 32 + q * 8);
                }
        }
        __syncthreads();   // drains global_load_lds (vmcnt) + xa, then barrier

        f32x4 acc[2][2] = {};
#pragma unroll
        for (int ksl = 0; ksl < 20; ++ksl) {
#pragma unroll
            for (int mt = 0; mt < 2; ++mt) {
                int row = mh * 32 + mt * 16 + c15;
                bf16x8 a;
                if (kh == 0 && ksl < 8) {
                    a = xa[ksl * 2 + mt];
                } else {
                    int kcol = kh * 640 + ksl * 32 + q * 8 - 256;   // h column
                    a = *(const bf16x8*)(smem + (size_t)(kcol >> 3) * 1024 + (size_t)row * 16);
                }
                acc[mt][0] = __builtin_amdgcn_mfma_f32_16x16x32_bf16(a, wreg[ksl],      acc[mt][0], 0, 0, 0);
                acc[mt][1] = __builtin_amdgcn_mfma_f32_16x16x32_bf16(a, wreg[20 + ksl], acc[mt][1], 0, 0, 0);
            }
        }
        if (kh == 1) {   // k-half-1 waves dump partials
            float* dp = (float*)(dumpbase + mh * 4096);
#pragma unroll
            for (int mt = 0; mt < 2; ++mt)
#pragma unroll
                for (int nt = 0; nt < 2; ++nt)
                    *(f32x4*)(dp + ((mt * 2 + nt) * 64 + lane) * 4) = acc[mt][nt];
        }
        __syncthreads();
        if (kh == 0) {   // reduce + gates + state update (waves 0,2 in parallel)
            const float* dp = (const float*)(dumpbase + mh * 4096);
            bool low = (lane & 8) == 0;
#pragma unroll
            for (int mt = 0; mt < 2; ++mt) {
                f32x4 g0 = acc[mt][0] + *(const f32x4*)(dp + ((mt * 2 + 0) * 64 + lane) * 4);
                f32x4 g1 = acc[mt][1] + *(const f32x4*)(dp + ((mt * 2 + 1) * 64 + lane) * 4);
                f32x4 av4;
#pragma unroll
                for (int r = 0; r < 4; ++r) {
                    float fo0 = __shfl(g0[r], lane ^ 8);   // f gate from partner lane
                    float fo1 = __shfl(g1[r], lane ^ 8);   // o gate from partner lane
                    int row = mh * 32 + mt * 16 + q * 4 + r;
                    float si = sigm(g0[r] + b_ii);
                    float sf = sigm(fo0 + b_ff);
                    float tg = tanhf(g1[r] + b_gg);
                    float so = sigm(fo1 + b_oo);
                    float cprev = auxf[row * 8 + hc];
                    float cn = sf * cprev + si * tg;
                    float hn = so * tanhf(cn);
                    float av = low ? hn * attw_l : 0.f;
                    av += __shfl_xor(av, 1); av += __shfl_xor(av, 2); av += __shfl_xor(av, 4);
                    av4[r] = av;
                    if (low) {
                        auxf[row * 8 + hc] = cn;
                        hscr[row * 8 + hc] = f2bf(hn);     // LDS transpose staging
                    }
                }
                if (c15 == 0)   // WT store: never dirty in L2 (per-step inv safety)
                    store_16B_wt(att_part + (size_t)bid * 32768 + tx * 64
                                 + (mh * 32 + mt * 16 + q * 4),
                                 __builtin_bit_cast(u32x4, av4));
            }
        }
        __syncthreads();   // hscr complete
        if (tid < 64) {    // block's 1KB region = chunks cg*64..cg*64+63: 16 full lines
            u32x4 v = *(const u32x4*)(hscr + tid * 8);
            store_16B_wt((char*)h_lstm + (size_t)(dir * 2 + ((t + 1) & 1)) * 131072
                         + (size_t)(cg * 64 + tid) * 16, v);
        }
        flag_light(flags, dir * 128, 128, dir * 128 + cg, (unsigned)(t + 1));
    }

    // =============== attention finalize ===============
    flag_barrier(flags, 256, 256, 256 + bid, 2u);   // heavy
    {
        int i = tid & 127, half = tid >> 7;
        int item = bid * 128 + i;               // = t*64 + row
        int tt = item >> 6, row = item & 63;
        float s = 0.f;
        const float* p = att_part + (size_t)half * 128 * 32768 + item;
        for (int blk = 0; blk < 128; ++blk)
            s += p[(size_t)blk * 32768];
        float* red = (float*)dumpbase;
        if (half) red[i] = s;
        __syncthreads();
        if (!half)
            out[BATCH * COUT + row * SEQ + tt] = sigm(ATT_SIG_W * (s + red[i] + att_fc_b[0]));
    }
    flag_barrier(flags, 256, 256, 256 + bid, 3u);   // heavy: att out cached-written
    if (bid >= 64) return;

    // =============== TAGM loop (64 blocks x 16 h-cols) ===============
    bf16x8 wt[20];
    {
        const unsigned short* wp = Wtp + (size_t)(bid * 2 + kh) * 10240;
#pragma unroll
        for (int f = 0; f < 20; ++f)
            wt[f] = *(const bf16x8*)(wp + f * 512 + lane * 8);
    }
    int colT = bid * 16 + c15;
    float bbT = i2h_b[colT] + h2h_b[colT];
    for (int i = tid; i < 1024; i += 256) auxf[i] = 0.f;   // h master [64][16]
    __syncthreads();
    const float* attd = out + BATCH * COUT;

    for (int t = 0; t < SEQ; ++t) {
        {   // stage: identity linear copy of blocked image, via L2
            const char* hsrc = (const char*)h_tagm + (size_t)(t & 1) * 131072;
            char* lbase = smem + (size_t)(tid & 192) * 16;
#pragma unroll
            for (int i = 0; i < 32; ++i) {
                int s = i * 256 + tid;
                GLOAD_LDS_CACHED(hsrc + (size_t)s * 16, lbase + (size_t)i * 4096);
            }
        }
        const unsigned short* xrow = xt + (size_t)t * BATCH * DIM;
        bf16x8 xa[16];
        if (kh == 0) {
#pragma unroll
            for (int ksl = 0; ksl < 8; ++ksl)
#pragma unroll
                for (int mt = 0; mt < 2; ++mt) {
                    int row = mh * 32 + mt * 16 + c15;
                    xa[ksl * 2 + mt] = *(const bf16x8*)(xrow + row * DIM + ksl * 32 + q * 8);
                }
        }
        __syncthreads();
        f32x4 acc[2] = {};
#pragma unroll
        for (int ksl = 0; ksl < 20; ++ksl) {
#pragma unroll
            for (int mt = 0; mt < 2; ++mt) {
                int row = mh * 32 + mt * 16 + c15;
                bf16x8 a;
                if (kh == 0 && ksl < 8) {
                    a = xa[ksl * 2 + mt];
                } else {
                    int kcol = kh * 640 + ksl * 32 + q * 8 - 256;
                    a = *(const bf16x8*)(smem + (size_t)(kcol >> 3) * 1024 + (size_t)row * 16);
                }
                acc[mt] = __builtin_amdgcn_mfma_f32_16x16x32_bf16(a, wt[ksl], acc[mt], 0, 0, 0);
            }
        }
        if (kh == 1) {
            float* dp = (float*)(dumpbase + mh * 2048);
            *(f32x4*)(dp + (0 * 64 + lane) * 4) = acc[0];
            *(f32x4*)(dp + (1 * 64 + lane) * 4) = acc[1];
        }
        __syncthreads();
        if (kh == 0) {
            const float* dp = (const float*)(dumpbase + mh * 2048);
#pragma unroll
            for (int mt = 0; mt < 2; ++mt) {
                f32x4 g = acc[mt] + *(const f32x4*)(dp + (mt * 64 + lane) * 4);
#pragma unroll
                for (int r = 0; r < 4; ++r) {
                    int row = mh * 32 + mt * 16 + q * 4 + r;
                    float cand = g[r] + bbT;
                    cand = cand > 0.f ? cand : 0.f;
                    float a = attd[row * SEQ + t];
                    float hold = auxf[row * 16 + c15];
                    float hn = a * cand + (1.f - a) * hold;
                    auxf[row * 16 + c15] = hn;
                    hscr[row * 16 + c15] = f2bf(hn);     // LDS transpose staging
                }
            }
        }
        __syncthreads();   // hscr complete
        if (tid < 128) {   // chunks (bid*2+nn)*64+row: 32 full lines, block-owned
            int nn = tid >> 6, row = tid & 63;
            u32x4 v = *(const u32x4*)(hscr + row * 16 + nn * 8);
            store_16B_wt((char*)h_tagm + (size_t)((t + 1) & 1) * 131072
                         + (size_t)((bid * 2 + nn) * 64 + row) * 16, v);
        }
        flag_light(flags, 512, 64, 512 + bid, (unsigned)(t + 1));
    }

    // dump final h (f32) for FC
    for (int i = tid; i < 1024; i += 256) {
        int row = i >> 4, cl = i & 15;
        h_f32[row * HID + bid * 16 + cl] = auxf[i];
    }
    flag_barrier(flags, 576, 64, 576 + bid, 1u);   // heavy: h_f32 cached-written

    // =============== FC: out[b][c], block = batch row ===============
    {
        float* fcp = (float*)dumpbase;   // [2][128]
        int c = tid & 127, half = tid >> 7;
        const float* hrow = h_f32 + (size_t)bid * HID;
        float s = 0.f;
        for (int k = half * 512; k < half * 512 + 512; ++k)
            s += hrow[k] * fc_w[(size_t)k * COUT + c];
        fcp[half * 128 + c] = s;
        __syncthreads();
        if (tid < 128)
            out[bid * COUT + tid] = fcp[tid] + fcp[128 + tid] + fc_b[tid];
    }
}

extern "C" void kernel_launch(void* const* d_in, const int* in_sizes, int n_in,
                              void* d_out, int out_size, void* d_ws, size_t ws_size,
                              hipStream_t stream) {
    const float* x          = (const float*)d_in[0];
    const float* i2h_w      = (const float*)d_in[1];
    const float* i2h_b      = (const float*)d_in[2];
    const float* h2h_w      = (const float*)d_in[3];
    const float* h2h_b      = (const float*)d_in[4];
    const float* fc_w       = (const float*)d_in[5];
    const float* fc_b       = (const float*)d_in[6];
    const float* att_wi_fwd = (const float*)d_in[7];
    const float* att_wh_fwd = (const float*)d_in[8];
    const float* att_b_fwd  = (const float*)d_in[9];
    const float* att_wi_bwd = (const float*)d_in[10];
    const float* att_wh_bwd = (const float*)d_in[11];
    const float* att_b_bwd  = (const float*)d_in[12];
    const float* att_fc_w   = (const float*)d_in[13];
    const float* att_fc_b   = (const float*)d_in[14];
    float* out = (float*)d_out;

    char* ws = (char*)d_ws;
    // setup-phase (dead after packs)
    unsigned short* WfT = (unsigned short*)(ws + 0);          // 10485760
    unsigned short* WbT = (unsigned short*)(ws + 10485760);   // 10485760
    unsigned short* WtT = (unsigned short*)(ws + 20971520);   // 2621440 -> 23592960
    // packed fragment weights
    unsigned short* Wfp = (unsigned short*)(ws + 23592960);   // 10485760
    unsigned short* Wbp = (unsigned short*)(ws + 34078720);   // 10485760 -> 44564480
    unsigned short* Wtp = (unsigned short*)(ws + 17829888);   // 2621440 -> 20451328 (survives)
    // runtime region
    unsigned short* xtb    = (unsigned short*)(ws + 0);        // 16777216
    unsigned short* h_lstm = (unsigned short*)(ws + 16777216); // 524288
    unsigned short* h_tagm = (unsigned short*)(ws + 17301504); // 262144
    float*          h_f32  = (float*)(ws + 17563648);          // 262144
    unsigned*       flags  = (unsigned*)(ws + 17825792);       // 4096 -> 17829888
    // att_part ALIASES Wfp/Wbp (weights register-resident after epoch-1 barrier)
    float*          att_part = (float*)(ws + 23592960);        // 33554432 -> 57147392

    transpose_weights<<<20 * (NGATE / 64), 256, 0, stream>>>(att_wi_fwd, att_wh_fwd, WfT, NGATE);
    transpose_weights<<<20 * (NGATE / 64), 256, 0, stream>>>(att_wi_bwd, att_wh_bwd, WbT, NGATE);
    transpose_weights<<<20 * (HID / 64), 256, 0, stream>>>(i2h_w, h2h_w, WtT, HID);
    pack_lstm<<<256, 256, 0, stream>>>(WfT, Wfp);
    pack_lstm<<<256, 256, 0, stream>>>(WbT, Wbp);
    pack_tagm<<<128, 256, 0, stream>>>(WtT, Wtp);
    transpose_x<<<(SEQ * BATCH * DIM + 255) / 256, 256, 0, stream>>>(x, xtb);
    // zero recurrent state + flags every call
    (void)hipMemsetAsync(ws + 16777216, 0, 17829888 - 16777216, stream);

    static const int SMEM_BYTES = 131072 + 8192 + 4096 + 2048;   // 145408
    (void)hipFuncSetAttribute(reinterpret_cast<const void*>(tagm_fused),
                              hipFuncAttributeMaxDynamicSharedMemorySize, SMEM_BYTES);
    tagm_fused<<<256, 256, SMEM_BYTES, stream>>>(
        xtb, Wfp, Wbp, Wtp, att_b_fwd, att_b_bwd, att_fc_w, att_fc_b,
        i2h_b, h2h_b, fc_w, fc_b, h_lstm, h_tagm, h_f32, att_part, flags, out);
}

// Round 12
// 8777.130 us; speedup vs baseline: 1.2374x; 1.2374x over previous
//
#include <hip/hip_runtime.h>
#include <hip/hip_bf16.h>
#include <cstdint>
#include <cstddef>

constexpr int BATCH = 64;
constexpr int SEQ   = 512;
constexpr int DIM   = 256;
constexpr int HID   = 1024;
constexpr int COUT  = 128;
constexpr int KTOT  = DIM + HID;   // 1280
constexpr int NGATE = 4 * HID;     // 4096
constexpr float ATT_SIG_W = 3.0f;

using bf16x8 = __attribute__((ext_vector_type(8))) __bf16;
using f32x4  = __attribute__((ext_vector_type(4))) float;
using u32x4  = __attribute__((ext_vector_type(4))) unsigned int;

__device__ __forceinline__ unsigned short f2bf(float f) {
    union { float f; unsigned u; } v; v.f = f;
    unsigned u = v.u;
    u += 0x7fffu + ((u >> 16) & 1u);
    return (unsigned short)(u >> 16);
}

__device__ __forceinline__ float sigm(float x) { return 1.f / (1.f + __expf(-x)); }

// 16B write-through store (sc0 sc1); payload must be ext_vector_type (reg quad)
__device__ __forceinline__ void store_16B_wt(void* p, u32x4 v) {
    asm volatile("global_store_dwordx4 %0, %1, off sc0 sc1"
                 :: "v"(p), "v"(v) : "memory");
}

// global->LDS direct copy, 16B/lane, sc0|sc1 (aux=17): bypass L1+L2, read coherent L3
// (R11 proved cached reads + per-step inv are a net loss; bypass is the right design)
#define GLOAD_LDS_COHERENT(gptr, lptr)                                     \
    __builtin_amdgcn_global_load_lds(                                      \
        (const __attribute__((address_space(1))) void*)(gptr),             \
        (__attribute__((address_space(3))) void*)(lptr), 16, 0, 17)

// ---- weight transpose+convert: out[n][k] = bf16( k<DIM ? wi[k][n] : wh[k-DIM][n] )
__global__ void transpose_weights(const float* __restrict__ wi,
                                  const float* __restrict__ wh,
                                  unsigned short* __restrict__ out, int N) {
    __shared__ float tile[64][65];
    int ntiles = N >> 6;
    int kt = blockIdx.x / ntiles;
    int nt = blockIdx.x % ntiles;
    int k0 = kt << 6, n0 = nt << 6;
    int a = threadIdx.x & 63, g = threadIdx.x >> 6;
#pragma unroll
    for (int p = 0; p < 16; ++p) {
        int kr = p * 4 + g;
        int k = k0 + kr;
        const float* src = (k < DIM) ? (wi + (size_t)k * N) : (wh + (size_t)(k - DIM) * N);
        tile[kr][a] = src[n0 + a];
    }
    __syncthreads();
#pragma unroll
    for (int p = 0; p < 16; ++p) {
        int nr = p * 4 + g;
        out[(size_t)(n0 + nr) * KTOT + (k0 + a)] = f2bf(tile[a][nr]);
    }
}

// ---- x [B][T][D] f32 -> xt [T][B][D] bf16
__global__ void transpose_x(const float* __restrict__ x, unsigned short* __restrict__ xt) {
    size_t idx = (size_t)blockIdx.x * blockDim.x + threadIdx.x;
    if (idx >= (size_t)SEQ * BATCH * DIM) return;
    int d = idx % DIM;
    size_t r = idx / DIM;
    int b = r % BATCH;
    int t = r / BATCH;
    xt[idx] = f2bf(x[((size_t)b * SEQ + t) * DIM + d]);
}

// ---- pack LSTM weights into per-(colgroup, khalf) MFMA fragment order.
__global__ void pack_lstm(const unsigned short* __restrict__ WT,
                          unsigned short* __restrict__ out) {
    int cg = blockIdx.x >> 1, kh = blockIdx.x & 1;
    size_t base = (size_t)blockIdx.x * 20480;
#pragma unroll
    for (int j = 0; j < 80; ++j) {
        int idx = threadIdx.x * 80 + j;
        int frag = idx >> 9;
        int rem = idx & 511;
        int lane = rem >> 3, e = rem & 7;
        int nt = frag / 20, ksl = frag % 20;
        int p = nt * 16 + (lane & 15);
        int origcol = (p >> 3) * 1024 + cg * 8 + (p & 7);
        int k = kh * 640 + ksl * 32 + ((lane >> 4) & 3) * 8 + e;
        out[base + idx] = WT[(size_t)origcol * KTOT + k];
    }
}

// ---- pack TAGM weights: region (cg,kh): 20 frags x 1024B; col = cg*16+(lane&15)
__global__ void pack_tagm(const unsigned short* __restrict__ WT,
                          unsigned short* __restrict__ out) {
    int cg = blockIdx.x >> 1, kh = blockIdx.x & 1;
    size_t base = (size_t)blockIdx.x * 10240;
#pragma unroll
    for (int j = 0; j < 40; ++j) {
        int idx = threadIdx.x * 40 + j;
        int ksl = idx >> 9;
        int rem = idx & 511;
        int lane = rem >> 3, e = rem & 7;
        int origcol = cg * 16 + (lane & 15);
        int k = kh * 640 + ksl * 32 + ((lane >> 4) & 3) * 8 + e;
        out[base + idx] = WT[(size_t)origcol * KTOT + k];
    }
}

// ---- block-wide light barrier (weights epoch only)
__device__ __forceinline__ void flag_light(unsigned* flags, int base, int cnt,
                                           int myidx, unsigned epoch) {
    asm volatile("s_waitcnt vmcnt(0)" ::: "memory");
    __syncthreads();
    if (threadIdx.x == 0)
        __hip_atomic_store(flags + myidx, epoch, __ATOMIC_RELAXED, __HIP_MEMORY_SCOPE_AGENT);
    if (threadIdx.x < 64) {
        for (;;) {
            bool ok = true;
            for (int j = (int)threadIdx.x; j < cnt; j += 64)
                ok &= (__hip_atomic_load(flags + base + j, __ATOMIC_RELAXED,
                                         __HIP_MEMORY_SCOPE_AGENT) >= epoch);
            if (__all(ok)) break;
            __builtin_amdgcn_s_sleep(1);
        }
    }
    __syncthreads();
}

// ---- HEAVY barrier (phase boundaries only): full release/acquire fences
__device__ __forceinline__ void flag_barrier(unsigned* flags, int base, int cnt,
                                             int myidx, unsigned epoch) {
    __syncthreads();
    if (threadIdx.x == 0) {
        __builtin_amdgcn_fence(__ATOMIC_RELEASE, "agent");   // wbl2
        __hip_atomic_store(flags + myidx, epoch, __ATOMIC_RELAXED, __HIP_MEMORY_SCOPE_AGENT);
    }
    if (threadIdx.x < 64) {
        for (;;) {
            bool ok = true;
            for (int j = (int)threadIdx.x; j < cnt; j += 64)
                ok &= (__hip_atomic_load(flags + base + j, __ATOMIC_RELAXED,
                                         __HIP_MEMORY_SCOPE_AGENT) >= epoch);
            if (__all(ok)) break;
            __builtin_amdgcn_s_sleep(1);
        }
        if (threadIdx.x == 0)
            __builtin_amdgcn_fence(__ATOMIC_ACQUIRE, "agent");   // inv
    }
    __syncthreads();
}

// ======== persistent fused kernel ========
// grid 256 x 256thr (VGPR ~208, no spill). R10 design + per-wave partitioned
// poll-and-stage: wave w polls only ITS 32 (LSTM) / 16 (TAGM) producers'
// flags, then immediately stages their chunks (its contiguous 32KB quarter of
// the LDS image) — the stage streams in while other waves still wait on their
// slowest producers. One syncthreads joins all quarters before the MFMAs.
// h layout BLOCKED: chunk s = cg8*64 + row, 16B/chunk; LDS image = identity.
__global__ __launch_bounds__(256)
void tagm_fused(const unsigned short* __restrict__ xt,
                const unsigned short* __restrict__ Wfp,
                const unsigned short* __restrict__ Wbp,
                const unsigned short* __restrict__ Wtp,
                const float* __restrict__ bias_f, const float* __restrict__ bias_b,
                const float* __restrict__ attw, const float* __restrict__ att_fc_b,
                const float* __restrict__ i2h_b, const float* __restrict__ h2h_b,
                const float* __restrict__ fc_w, const float* __restrict__ fc_b,
                unsigned short* __restrict__ h_lstm,  // [2 dir][2 buf] x 128KB blocked
                unsigned short* __restrict__ h_tagm,  // [2 buf] x 128KB blocked
                float* __restrict__ h_f32,            // [64][1024]
                float* __restrict__ att_part,         // [256 blk][512*64] f32 (aliases Wfp/Wbp!)
                unsigned* __restrict__ flags,         // [640]
                float* __restrict__ out) {
    extern __shared__ char smem[];                   // [0,131072): blocked h image
    char* dumpbase = smem + 131072;                  // 8 KB acc dump
    float* auxf = (float*)(smem + 131072 + 8192);    // 4 KB: LSTM c / TAGM h master
    unsigned short* hscr = (unsigned short*)(smem + 131072 + 8192 + 4096);  // 2 KB

    int tid = threadIdx.x;
    int wave = tid >> 6, lane = tid & 63;
    int bid = blockIdx.x;
    int dir = bid & 1, cg = bid >> 1;
    int mh = wave >> 1, kh = wave & 1;
    int q = lane >> 4, c15 = lane & 15;

    // ---- LSTM weight fragments -> registers
    bf16x8 wreg[40];
    {
        const unsigned short* wp = (dir ? Wbp : Wfp) + (size_t)(cg * 2 + kh) * 20480;
#pragma unroll
        for (int f = 0; f < 40; ++f)
            wreg[f] = *(const bf16x8*)(wp + f * 512 + lane * 8);
    }
    int hc = lane & 7;
    int colE = cg * 8 + hc;
    const float* bias = dir ? bias_b : bias_f;
    float b_ii = bias[colE], b_ff = bias[HID + colE];
    float b_gg = bias[2 * HID + colE], b_oo = bias[3 * HID + colE];
    float attw_l = attw[dir * HID + colE];

    for (int i = tid; i < 512; i += 256) auxf[i] = 0.f;   // c = 0

    // weights in regs before att_part clobbers Wfp/Wbp
    flag_light(flags, 256, 256, 256 + bid, 1u);

    // =============== LSTM loop ===============
    for (int t = 0; t < SEQ; ++t) {
        int tx = dir ? (SEQ - 1 - t) : t;
        // x prefetch first (independent of flags; overlaps poll RTT)
        const unsigned short* xrow = xt + (size_t)tx * BATCH * DIM;
        bf16x8 xa[16];
        if (kh == 0) {
#pragma unroll
            for (int ksl = 0; ksl < 8; ++ksl)
#pragma unroll
                for (int mt = 0; mt < 2; ++mt) {
                    int row = mh * 32 + mt * 16 + c15;
                    xa[ksl * 2 + mt] = *(const bf16x8*)(xrow + row * DIM + ksl * 32 + q * 8);
                }
        }
        // per-wave: poll MY 32 producers (epoch >= t), then stage their 32KB
        if (t > 0) {
            for (;;) {
                bool ok = true;
                if (lane < 32)
                    ok = (__hip_atomic_load(flags + dir * 128 + wave * 32 + lane,
                                            __ATOMIC_RELAXED,
                                            __HIP_MEMORY_SCOPE_AGENT) >= (unsigned)t);
                if (__all(ok)) break;
                __builtin_amdgcn_s_sleep(1);
            }
        }
        __builtin_amdgcn_sched_barrier(0);   // don't hoist stage loads above poll
        {
            const char* hsrc = (const char*)h_lstm + (size_t)(dir * 2 + (t & 1)) * 131072;
            char* lbase = smem + (size_t)wave * 32768 + (size_t)lane * 16;
#pragma unroll
            for (int i = 0; i < 32; ++i) {
                int s = wave * 2048 + i * 64 + lane;   // chunk index (identity image)
                GLOAD_LDS_COHERENT(hsrc + (size_t)s * 16, lbase + (size_t)i * 1024);
            }
        }
        __syncthreads();   // all quarters staged (vmcnt drained by compiler)

        f32x4 acc[2][2] = {};
#pragma unroll
        for (int ksl = 0; ksl < 20; ++ksl) {
#pragma unroll
            for (int mt = 0; mt < 2; ++mt) {
                int row = mh * 32 + mt * 16 + c15;
                bf16x8 a;
                if (kh == 0 && ksl < 8) {
                    a = xa[ksl * 2 + mt];
                } else {
                    int kcol = kh * 640 + ksl * 32 + q * 8 - 256;   // h column
                    a = *(const bf16x8*)(smem + (size_t)(kcol >> 3) * 1024 + (size_t)row * 16);
                }
                acc[mt][0] = __builtin_amdgcn_mfma_f32_16x16x32_bf16(a, wreg[ksl],      acc[mt][0], 0, 0, 0);
                acc[mt][1] = __builtin_amdgcn_mfma_f32_16x16x32_bf16(a, wreg[20 + ksl], acc[mt][1], 0, 0, 0);
            }
        }
        if (kh == 1) {   // k-half-1 waves dump partials
            float* dp = (float*)(dumpbase + mh * 4096);
#pragma unroll
            for (int mt = 0; mt < 2; ++mt)
#pragma unroll
                for (int nt = 0; nt < 2; ++nt)
                    *(f32x4*)(dp + ((mt * 2 + nt) * 64 + lane) * 4) = acc[mt][nt];
        }
        __syncthreads();
        if (kh == 0) {   // reduce + gates + state update (waves 0,2 in parallel)
            const float* dp = (const float*)(dumpbase + mh * 4096);
            bool low = (lane & 8) == 0;
#pragma unroll
            for (int mt = 0; mt < 2; ++mt) {
                f32x4 g0 = acc[mt][0] + *(const f32x4*)(dp + ((mt * 2 + 0) * 64 + lane) * 4);
                f32x4 g1 = acc[mt][1] + *(const f32x4*)(dp + ((mt * 2 + 1) * 64 + lane) * 4);
                f32x4 av4;
#pragma unroll
                for (int r = 0; r < 4; ++r) {
                    float fo0 = __shfl(g0[r], lane ^ 8);   // f gate from partner lane
                    float fo1 = __shfl(g1[r], lane ^ 8);   // o gate from partner lane
                    int row = mh * 32 + mt * 16 + q * 4 + r;
                    float si = sigm(g0[r] + b_ii);
                    float sf = sigm(fo0 + b_ff);
                    float tg = tanhf(g1[r] + b_gg);
                    float so = sigm(fo1 + b_oo);
                    float cprev = auxf[row * 8 + hc];
                    float cn = sf * cprev + si * tg;
                    float hn = so * tanhf(cn);
                    float av = low ? hn * attw_l : 0.f;
                    av += __shfl_xor(av, 1); av += __shfl_xor(av, 2); av += __shfl_xor(av, 4);
                    av4[r] = av;
                    if (low) {
                        auxf[row * 8 + hc] = cn;
                        hscr[row * 8 + hc] = f2bf(hn);     // LDS transpose staging
                    }
                }
                if (c15 == 0)
                    *(f32x4*)(att_part + (size_t)bid * 32768 + tx * 64 + (mh * 32 + mt * 16 + q * 4)) = av4;
            }
        }
        __syncthreads();   // hscr complete; smem h image now dead (safe to re-stage)
        if (tid < 64) {    // wave 0: 16 full-line WT stores + drain + flag post
            u32x4 v = *(const u32x4*)(hscr + tid * 8);
            store_16B_wt((char*)h_lstm + (size_t)(dir * 2 + ((t + 1) & 1)) * 131072
                         + (size_t)(cg * 64 + tid) * 16, v);
            asm volatile("s_waitcnt vmcnt(0)" ::: "memory");
            if (tid == 0)
                __hip_atomic_store(flags + dir * 128 + cg, (unsigned)(t + 1),
                                   __ATOMIC_RELAXED, __HIP_MEMORY_SCOPE_AGENT);
        }
        // no trailing barrier: next iteration's per-wave poll + syncthreads covers it
    }

    // =============== attention finalize ===============
    flag_barrier(flags, 256, 256, 256 + bid, 2u);   // heavy: att_part cached-written
    {
        int i = tid & 127, half = tid >> 7;
        int item = bid * 128 + i;               // = t*64 + row
        int tt = item >> 6, row = item & 63;
        float s = 0.f;
        const float* p = att_part + (size_t)half * 128 * 32768 + item;
        for (int blk = 0; blk < 128; ++blk)
            s += p[(size_t)blk * 32768];
        float* red = (float*)dumpbase;
        if (half) red[i] = s;
        __syncthreads();
        if (!half)
            out[BATCH * COUT + row * SEQ + tt] = sigm(ATT_SIG_W * (s + red[i] + att_fc_b[0]));
    }
    flag_barrier(flags, 256, 256, 256 + bid, 3u);   // heavy: att out cached-written
    if (bid >= 64) return;

    // =============== TAGM loop (64 blocks x 16 h-cols) ===============
    bf16x8 wt[20];
    {
        const unsigned short* wp = Wtp + (size_t)(bid * 2 + kh) * 10240;
#pragma unroll
        for (int f = 0; f < 20; ++f)
            wt[f] = *(const bf16x8*)(wp + f * 512 + lane * 8);
    }
    int colT = bid * 16 + c15;
    float bbT = i2h_b[colT] + h2h_b[colT];
    for (int i = tid; i < 1024; i += 256) auxf[i] = 0.f;   // h master [64][16]
    __syncthreads();
    const float* attd = out + BATCH * COUT;

    for (int t = 0; t < SEQ; ++t) {
        const unsigned short* xrow = xt + (size_t)t * BATCH * DIM;
        bf16x8 xa[16];
        if (kh == 0) {
#pragma unroll
            for (int ksl = 0; ksl < 8; ++ksl)
#pragma unroll
                for (int mt = 0; mt < 2; ++mt) {
                    int row = mh * 32 + mt * 16 + c15;
                    xa[ksl * 2 + mt] = *(const bf16x8*)(xrow + row * DIM + ksl * 32 + q * 8);
                }
        }
        // per-wave: poll MY 16 producers, then stage their 32KB quarter
        if (t > 0) {
            for (;;) {
                bool ok = true;
                if (lane < 16)
                    ok = (__hip_atomic_load(flags + 512 + wave * 16 + lane,
                                            __ATOMIC_RELAXED,
                                            __HIP_MEMORY_SCOPE_AGENT) >= (unsigned)t);
                if (__all(ok)) break;
                __builtin_amdgcn_s_sleep(1);
            }
        }
        __builtin_amdgcn_sched_barrier(0);
        {
            const char* hsrc = (const char*)h_tagm + (size_t)(t & 1) * 131072;
            char* lbase = smem + (size_t)wave * 32768 + (size_t)lane * 16;
#pragma unroll
            for (int i = 0; i < 32; ++i) {
                int s = wave * 2048 + i * 64 + lane;
                GLOAD_LDS_COHERENT(hsrc + (size_t)s * 16, lbase + (size_t)i * 1024);
            }
        }
        __syncthreads();
        f32x4 acc[2] = {};
#pragma unroll
        for (int ksl = 0; ksl < 20; ++ksl) {
#pragma unroll
            for (int mt = 0; mt < 2; ++mt) {
                int row = mh * 32 + mt * 16 + c15;
                bf16x8 a;
                if (kh == 0 && ksl < 8) {
                    a = xa[ksl * 2 + mt];
                } else {
                    int kcol = kh * 640 + ksl * 32 + q * 8 - 256;
                    a = *(const bf16x8*)(smem + (size_t)(kcol >> 3) * 1024 + (size_t)row * 16);
                }
                acc[mt] = __builtin_amdgcn_mfma_f32_16x16x32_bf16(a, wt[ksl], acc[mt], 0, 0, 0);
            }
        }
        if (kh == 1) {
            float* dp = (float*)(dumpbase + mh * 2048);
            *(f32x4*)(dp + (0 * 64 + lane) * 4) = acc[0];
            *(f32x4*)(dp + (1 * 64 + lane) * 4) = acc[1];
        }
        __syncthreads();
        if (kh == 0) {
            const float* dp = (const float*)(dumpbase + mh * 2048);
#pragma unroll
            for (int mt = 0; mt < 2; ++mt) {
                f32x4 g = acc[mt] + *(const f32x4*)(dp + (mt * 64 + lane) * 4);
#pragma unroll
                for (int r = 0; r < 4; ++r) {
                    int row = mh * 32 + mt * 16 + q * 4 + r;
                    float cand = g[r] + bbT;
                    cand = cand > 0.f ? cand : 0.f;
                    float a = attd[row * SEQ + t];
                    float hold = auxf[row * 16 + c15];
                    float hn = a * cand + (1.f - a) * hold;
                    auxf[row * 16 + c15] = hn;
                    hscr[row * 16 + c15] = f2bf(hn);     // LDS transpose staging
                }
            }
        }
        __syncthreads();   // hscr complete; smem image dead
        if (tid < 64) {    // wave 0: 32 full lines (2 stores/thread) + drain + post
#pragma unroll
            for (int k2 = 0; k2 < 2; ++k2) {
                int idx = k2 * 64 + tid;           // chunk-in-block 0..127
                int nn = idx >> 6, row = idx & 63;
                u32x4 v = *(const u32x4*)(hscr + row * 16 + nn * 8);
                store_16B_wt((char*)h_tagm + (size_t)((t + 1) & 1) * 131072
                             + (size_t)((bid * 2 + nn) * 64 + row) * 16, v);
            }
            asm volatile("s_waitcnt vmcnt(0)" ::: "memory");
            if (tid == 0)
                __hip_atomic_store(flags + 512 + bid, (unsigned)(t + 1),
                                   __ATOMIC_RELAXED, __HIP_MEMORY_SCOPE_AGENT);
        }
    }

    // dump final h (f32) for FC
    for (int i = tid; i < 1024; i += 256) {
        int row = i >> 4, cl = i & 15;
        h_f32[row * HID + bid * 16 + cl] = auxf[i];
    }
    flag_barrier(flags, 576, 64, 576 + bid, 1u);   // heavy: h_f32 cached-written

    // =============== FC: out[b][c], block = batch row ===============
    {
        float* fcp = (float*)dumpbase;   // [2][128]
        int c = tid & 127, half = tid >> 7;
        const float* hrow = h_f32 + (size_t)bid * HID;
        float s = 0.f;
        for (int k = half * 512; k < half * 512 + 512; ++k)
            s += hrow[k] * fc_w[(size_t)k * COUT + c];
        fcp[half * 128 + c] = s;
        __syncthreads();
        if (tid < 128)
            out[bid * COUT + tid] = fcp[tid] + fcp[128 + tid] + fc_b[tid];
    }
}

extern "C" void kernel_launch(void* const* d_in, const int* in_sizes, int n_in,
                              void* d_out, int out_size, void* d_ws, size_t ws_size,
                              hipStream_t stream) {
    const float* x          = (const float*)d_in[0];
    const float* i2h_w      = (const float*)d_in[1];
    const float* i2h_b      = (const float*)d_in[2];
    const float* h2h_w      = (const float*)d_in[3];
    const float* h2h_b      = (const float*)d_in[4];
    const float* fc_w       = (const float*)d_in[5];
    const float* fc_b       = (const float*)d_in[6];
    const float* att_wi_fwd = (const float*)d_in[7];
    const float* att_wh_fwd = (const float*)d_in[8];
    const float* att_b_fwd  = (const float*)d_in[9];
    const float* att_wi_bwd = (const float*)d_in[10];
    const float* att_wh_bwd = (const float*)d_in[11];
    const float* att_b_bwd  = (const float*)d_in[12];
    const float* att_fc_w   = (const float*)d_in[13];
    const float* att_fc_b   = (const float*)d_in[14];
    float* out = (float*)d_out;

    char* ws = (char*)d_ws;
    // setup-phase (dead after packs)
    unsigned short* WfT = (unsigned short*)(ws + 0);          // 10485760
    unsigned short* WbT = (unsigned short*)(ws + 10485760);   // 10485760
    unsigned short* WtT = (unsigned short*)(ws + 20971520);   // 2621440 -> 23592960
    // packed fragment weights
    unsigned short* Wfp = (unsigned short*)(ws + 23592960);   // 10485760
    unsigned short* Wbp = (unsigned short*)(ws + 34078720);   // 10485760 -> 44564480
    unsigned short* Wtp = (unsigned short*)(ws + 17829888);   // 2621440 -> 20451328 (survives)
    // runtime region
    unsigned short* xtb    = (unsigned short*)(ws + 0);        // 16777216
    unsigned short* h_lstm = (unsigned short*)(ws + 16777216); // 524288
    unsigned short* h_tagm = (unsigned short*)(ws + 17301504); // 262144
    float*          h_f32  = (float*)(ws + 17563648);          // 262144
    unsigned*       flags  = (unsigned*)(ws + 17825792);       // 4096 -> 17829888
    // att_part ALIASES Wfp/Wbp (weights register-resident after epoch-1 barrier)
    float*          att_part = (float*)(ws + 23592960);        // 33554432 -> 57147392

    transpose_weights<<<20 * (NGATE / 64), 256, 0, stream>>>(att_wi_fwd, att_wh_fwd, WfT, NGATE);
    transpose_weights<<<20 * (NGATE / 64), 256, 0, stream>>>(att_wi_bwd, att_wh_bwd, WbT, NGATE);
    transpose_weights<<<20 * (HID / 64), 256, 0, stream>>>(i2h_w, h2h_w, WtT, HID);
    pack_lstm<<<256, 256, 0, stream>>>(WfT, Wfp);
    pack_lstm<<<256, 256, 0, stream>>>(WbT, Wbp);
    pack_tagm<<<128, 256, 0, stream>>>(WtT, Wtp);
    transpose_x<<<(SEQ * BATCH * DIM + 255) / 256, 256, 0, stream>>>(x, xtb);
    // zero recurrent state + flags every call
    (void)hipMemsetAsync(ws + 16777216, 0, 17829888 - 16777216, stream);

    static const int SMEM_BYTES = 131072 + 8192 + 4096 + 2048;   // 145408
    (void)hipFuncSetAttribute(reinterpret_cast<const void*>(tagm_fused),
                              hipFuncAttributeMaxDynamicSharedMemorySize, SMEM_BYTES);
    tagm_fused<<<256, 256, SMEM_BYTES, stream>>>(
        xtb, Wfp, Wbp, Wtp, att_b_fwd, att_b_bwd, att_fc_w, att_fc_b,
        i2h_b, h2h_b, fc_w, fc_b, h_lstm, h_tagm, h_f32, att_part, flags, out);
}

// Round 13
// 6406.121 us; speedup vs baseline: 1.6954x; 1.3701x over previous
//
#include <hip/hip_runtime.h>
#include <hip/hip_bf16.h>
#include <cstdint>
#include <cstddef>

constexpr int BATCH = 64;
constexpr int SEQ   = 512;
constexpr int DIM   = 256;
constexpr int HID   = 1024;
constexpr int COUT  = 128;
constexpr int KTOT  = DIM + HID;   // 1280
constexpr int NGATE = 4 * HID;     // 4096
constexpr float ATT_SIG_W = 3.0f;

using bf16x8 = __attribute__((ext_vector_type(8))) __bf16;
using f32x4  = __attribute__((ext_vector_type(4))) float;
using u32x4  = __attribute__((ext_vector_type(4))) unsigned int;

__device__ __forceinline__ unsigned short f2bf(float f) {
    union { float f; unsigned u; } v; v.f = f;
    unsigned u = v.u;
    u += 0x7fffu + ((u >> 16) & 1u);
    return (unsigned short)(u >> 16);
}

__device__ __forceinline__ float sigm(float x) { return 1.f / (1.f + __expf(-x)); }

// 16B write-through store (sc0 sc1); payload must be ext_vector_type (reg quad)
__device__ __forceinline__ void store_16B_wt(void* p, u32x4 v) {
    asm volatile("global_store_dwordx4 %0, %1, off sc0 sc1"
                 :: "v"(p), "v"(v) : "memory");
}

// global->LDS direct copy, 16B/lane, sc0|sc1 (aux=17): bypass L1+L2, read coherent L3
#define GLOAD_LDS_COHERENT(gptr, lptr)                                     \
    __builtin_amdgcn_global_load_lds(                                      \
        (const __attribute__((address_space(1))) void*)(gptr),             \
        (__attribute__((address_space(3))) void*)(lptr), 16, 0, 17)

// ---- weight transpose+convert: out[n][k] = bf16( k<DIM ? wi[k][n] : wh[k-DIM][n] )
__global__ void transpose_weights(const float* __restrict__ wi,
                                  const float* __restrict__ wh,
                                  unsigned short* __restrict__ out, int N) {
    __shared__ float tile[64][65];
    int ntiles = N >> 6;
    int kt = blockIdx.x / ntiles;
    int nt = blockIdx.x % ntiles;
    int k0 = kt << 6, n0 = nt << 6;
    int a = threadIdx.x & 63, g = threadIdx.x >> 6;
#pragma unroll
    for (int p = 0; p < 16; ++p) {
        int kr = p * 4 + g;
        int k = k0 + kr;
        const float* src = (k < DIM) ? (wi + (size_t)k * N) : (wh + (size_t)(k - DIM) * N);
        tile[kr][a] = src[n0 + a];
    }
    __syncthreads();
#pragma unroll
    for (int p = 0; p < 16; ++p) {
        int nr = p * 4 + g;
        out[(size_t)(n0 + nr) * KTOT + (k0 + a)] = f2bf(tile[a][nr]);
    }
}

// ---- x [B][T][D] f32 -> xt [T][B][D] bf16
__global__ void transpose_x(const float* __restrict__ x, unsigned short* __restrict__ xt) {
    size_t idx = (size_t)blockIdx.x * blockDim.x + threadIdx.x;
    if (idx >= (size_t)SEQ * BATCH * DIM) return;
    int d = idx % DIM;
    size_t r = idx / DIM;
    int b = r % BATCH;
    int t = r / BATCH;
    xt[idx] = f2bf(x[((size_t)b * SEQ + t) * DIM + d]);
}

// ---- pack LSTM weights into per-(colgroup8, khalf) MFMA fragment order (unchanged)
__global__ void pack_lstm(const unsigned short* __restrict__ WT,
                          unsigned short* __restrict__ out) {
    int cg = blockIdx.x >> 1, kh = blockIdx.x & 1;
    size_t base = (size_t)blockIdx.x * 20480;
#pragma unroll
    for (int j = 0; j < 80; ++j) {
        int idx = threadIdx.x * 80 + j;
        int frag = idx >> 9;
        int rem = idx & 511;
        int lane = rem >> 3, e = rem & 7;
        int nt = frag / 20, ksl = frag % 20;
        int p = nt * 16 + (lane & 15);
        int origcol = (p >> 3) * 1024 + cg * 8 + (p & 7);
        int k = kh * 640 + ksl * 32 + ((lane >> 4) & 3) * 8 + e;
        out[base + idx] = WT[(size_t)origcol * KTOT + k];
    }
}

// ---- pack TAGM weights: region (cg16, kh): 20 frags x 1024B; col = cg*16+(lane&15)
__global__ void pack_tagm(const unsigned short* __restrict__ WT,
                          unsigned short* __restrict__ out) {
    int cg = blockIdx.x >> 1, kh = blockIdx.x & 1;
    size_t base = (size_t)blockIdx.x * 10240;
#pragma unroll
    for (int j = 0; j < 40; ++j) {
        int idx = threadIdx.x * 40 + j;
        int ksl = idx >> 9;
        int rem = idx & 511;
        int lane = rem >> 3, e = rem & 7;
        int origcol = cg * 16 + (lane & 15);
        int k = kh * 640 + ksl * 32 + ((lane >> 4) & 3) * 8 + e;
        out[base + idx] = WT[(size_t)origcol * KTOT + k];
    }
}

// ---- block-wide light barrier (weights epoch only)
__device__ __forceinline__ void flag_light(unsigned* flags, int base, int cnt,
                                           int myidx, unsigned epoch) {
    asm volatile("s_waitcnt vmcnt(0)" ::: "memory");
    __syncthreads();
    if (threadIdx.x == 0)
        __hip_atomic_store(flags + myidx, epoch, __ATOMIC_RELAXED, __HIP_MEMORY_SCOPE_AGENT);
    if (threadIdx.x < 64) {
        for (;;) {
            bool ok = true;
            for (int j = (int)threadIdx.x; j < cnt; j += 64)
                ok &= (__hip_atomic_load(flags + base + j, __ATOMIC_RELAXED,
                                         __HIP_MEMORY_SCOPE_AGENT) >= epoch);
            if (__all(ok)) break;
            __builtin_amdgcn_s_sleep(1);
        }
    }
    __syncthreads();
}

// ---- HEAVY barrier (phase boundaries only): full release/acquire fences
__device__ __forceinline__ void flag_barrier(unsigned* flags, int base, int cnt,
                                             int myidx, unsigned epoch) {
    __syncthreads();
    if (threadIdx.x == 0) {
        __builtin_amdgcn_fence(__ATOMIC_RELEASE, "agent");   // wbl2
        __hip_atomic_store(flags + myidx, epoch, __ATOMIC_RELAXED, __HIP_MEMORY_SCOPE_AGENT);
    }
    if (threadIdx.x < 64) {
        for (;;) {
            bool ok = true;
            for (int j = (int)threadIdx.x; j < cnt; j += 64)
                ok &= (__hip_atomic_load(flags + base + j, __ATOMIC_RELAXED,
                                         __HIP_MEMORY_SCOPE_AGENT) >= epoch);
            if (__all(ok)) break;
            __builtin_amdgcn_s_sleep(1);
        }
        if (threadIdx.x == 0)
            __builtin_amdgcn_fence(__ATOMIC_ACQUIRE, "agent");   // inv
    }
    __syncthreads();
}

// ======== persistent fused kernel ========
// 2-D split: LSTM block = (dir = bid&1, rh = (bid>>1)&1 : 32 batch rows,
// cg = bid>>2 : 16 h-cols). Stage = only its row-half's h = 64 KB (was 128):
// broadcast volume 32->16 MB/step. Wave = (nc = w>>1, kh = w&1): 32 packed
// gate-cols x 640 K in 160 VGPR (same as before), M=32, 80 MFMAs/wave.
// h layout [dir][buf][rh] 64KB: chunk s = cg*64 + ch*32 + row (ch = 8-col half
// of block's 16 cols) -> block writes contiguous 1KB; stage identity-coalesced;
// LDS frag read = (kcol>>4)*1024 + ((kcol>>3)&1)*512 + row*16 (16B stride, free).
// TAGM (bid<128): block = (rh = bid&1, cg = bid>>1 : 16 cols); wave = (mh, kh).
__global__ __launch_bounds__(256)
void tagm_fused(const unsigned short* __restrict__ xt,
                const unsigned short* __restrict__ Wfp,
                const unsigned short* __restrict__ Wbp,
                const unsigned short* __restrict__ Wtp,
                const float* __restrict__ bias_f, const float* __restrict__ bias_b,
                const float* __restrict__ attw, const float* __restrict__ att_fc_b,
                const float* __restrict__ i2h_b, const float* __restrict__ h2h_b,
                const float* __restrict__ fc_w, const float* __restrict__ fc_b,
                unsigned short* __restrict__ h_lstm,  // [2 dir][2 buf][2 rh] x 64KB
                unsigned short* __restrict__ h_tagm,  // [2 buf][2 rh] x 64KB
                float* __restrict__ h_f32,            // [64][1024]
                float* __restrict__ att_part,         // [512 slots][512t*32] f32 (aliases Wfp/Wbp!)
                unsigned* __restrict__ flags,         // [1024]
                float* __restrict__ out) {
    extern __shared__ char smem[];                   // [0,65536): blocked h image (row-half)
    char* dumpbase = smem + 65536;                   // 8 KB acc dump
    float* auxf = (float*)(smem + 65536 + 8192);     // 4 KB: LSTM c / TAGM h master
    unsigned short* hscr = (unsigned short*)(smem + 65536 + 8192 + 4096);  // 2 KB

    int tid = threadIdx.x;
    int wave = tid >> 6, lane = tid & 63;
    int bid = blockIdx.x;
    int dir = bid & 1, rh = (bid >> 1) & 1, cg = bid >> 2;   // cg in [0,64)
    int nc = wave >> 1, kh = wave & 1;
    int q = lane >> 4, c15 = lane & 15;
    int hc = lane & 7;

    // ---- LSTM weight fragments -> registers (region cg8 = cg*2+nc, khalf kh)
    bf16x8 wreg[40];
    {
        const unsigned short* wp = (dir ? Wbp : Wfp)
                                   + (size_t)((cg * 2 + nc) * 2 + kh) * 20480;
#pragma unroll
        for (int f = 0; f < 40; ++f)
            wreg[f] = *(const bf16x8*)(wp + f * 512 + lane * 8);
    }
    int colE = cg * 16 + nc * 8 + hc;
    const float* bias = dir ? bias_b : bias_f;
    float b_ii = bias[colE], b_ff = bias[HID + colE];
    float b_gg = bias[2 * HID + colE], b_oo = bias[3 * HID + colE];
    float attw_l = attw[dir * HID + colE];

    for (int i = tid; i < 512; i += 256) auxf[i] = 0.f;   // c-state [32 rows][16 cols]

    // weights in regs before att_part clobbers Wfp/Wbp
    flag_light(flags, 256, 256, 256 + bid, 1u);

    // =============== LSTM loop ===============
    for (int t = 0; t < SEQ; ++t) {
        int tx = dir ? (SEQ - 1 - t) : t;
        const unsigned short* xrow = xt + (size_t)tx * BATCH * DIM;
        bf16x8 xa[16];
        if (kh == 0) {
#pragma unroll
            for (int ksl = 0; ksl < 8; ++ksl)
#pragma unroll
                for (int mt = 0; mt < 2; ++mt) {
                    int row = rh * 32 + mt * 16 + c15;
                    xa[ksl * 2 + mt] = *(const bf16x8*)(xrow + row * DIM + ksl * 32 + q * 8);
                }
        }
        // per-wave: poll MY 16 producers of group (dir, rh), then stage their 16KB
        if (t > 0) {
            for (;;) {
                bool ok = true;
                if (lane < 16)
                    ok = (__hip_atomic_load(flags + dir * 128 + rh * 64 + wave * 16 + lane,
                                            __ATOMIC_RELAXED,
                                            __HIP_MEMORY_SCOPE_AGENT) >= (unsigned)t);
                if (__all(ok)) break;
                __builtin_amdgcn_s_sleep(1);
            }
        }
        __builtin_amdgcn_sched_barrier(0);   // don't hoist stage loads above poll
        {
            const char* hsrc = (const char*)h_lstm
                               + (size_t)((dir * 2 + (t & 1)) * 2 + rh) * 65536;
            char* lbase = smem + (size_t)wave * 16384 + (size_t)lane * 16;
#pragma unroll
            for (int i = 0; i < 16; ++i) {
                int s = wave * 1024 + i * 64 + lane;   // chunk index (identity image)
                GLOAD_LDS_COHERENT(hsrc + (size_t)s * 16, lbase + (size_t)i * 1024);
            }
        }
        __syncthreads();   // all quarters staged

        f32x4 acc[2][2] = {};
#pragma unroll
        for (int ksl = 0; ksl < 20; ++ksl) {
#pragma unroll
            for (int mt = 0; mt < 2; ++mt) {
                bf16x8 a;
                if (kh == 0 && ksl < 8) {
                    a = xa[ksl * 2 + mt];
                } else {
                    int kcol = kh * 640 + ksl * 32 + q * 8 - 256;   // h column 0..1023
                    a = *(const bf16x8*)(smem + (size_t)(kcol >> 4) * 1024
                                         + (size_t)((kcol >> 3) & 1) * 512
                                         + (size_t)(mt * 16 + c15) * 16);
                }
                acc[mt][0] = __builtin_amdgcn_mfma_f32_16x16x32_bf16(a, wreg[ksl],      acc[mt][0], 0, 0, 0);
                acc[mt][1] = __builtin_amdgcn_mfma_f32_16x16x32_bf16(a, wreg[20 + ksl], acc[mt][1], 0, 0, 0);
            }
        }
        if (kh == 1) {   // dump partials to slot nc
            float* dp = (float*)(dumpbase + nc * 4096);
#pragma unroll
            for (int mt = 0; mt < 2; ++mt)
#pragma unroll
                for (int nt = 0; nt < 2; ++nt)
                    *(f32x4*)(dp + ((mt * 2 + nt) * 64 + lane) * 4) = acc[mt][nt];
        }
        __syncthreads();
        if (kh == 0) {   // reduce + gates + state update (waves 0,2 in parallel)
            const float* dp = (const float*)(dumpbase + nc * 4096);
            bool low = (lane & 8) == 0;
#pragma unroll
            for (int mt = 0; mt < 2; ++mt) {
                f32x4 g0 = acc[mt][0] + *(const f32x4*)(dp + ((mt * 2 + 0) * 64 + lane) * 4);
                f32x4 g1 = acc[mt][1] + *(const f32x4*)(dp + ((mt * 2 + 1) * 64 + lane) * 4);
                f32x4 av4;
#pragma unroll
                for (int r = 0; r < 4; ++r) {
                    float fo0 = __shfl(g0[r], lane ^ 8);   // f gate from partner lane
                    float fo1 = __shfl(g1[r], lane ^ 8);   // o gate from partner lane
                    int rl = mt * 16 + q * 4 + r;          // local row 0..31
                    float si = sigm(g0[r] + b_ii);
                    float sf = sigm(fo0 + b_ff);
                    float tg = tanhf(g1[r] + b_gg);
                    float so = sigm(fo1 + b_oo);
                    float cprev = auxf[rl * 16 + nc * 8 + hc];
                    float cn = sf * cprev + si * tg;
                    float hn = so * tanhf(cn);
                    float av = low ? hn * attw_l : 0.f;
                    av += __shfl_xor(av, 1); av += __shfl_xor(av, 2); av += __shfl_xor(av, 4);
                    av4[r] = av;
                    if (low) {
                        auxf[rl * 16 + nc * 8 + hc] = cn;
                        hscr[nc * 256 + rl * 8 + hc] = f2bf(hn);   // [ch=nc][row][8col]
                    }
                }
                if (c15 == 0)
                    *(f32x4*)(att_part + (size_t)(bid * 2 + nc) * 16384
                              + (size_t)tx * 32 + (mt * 16 + q * 4)) = av4;
            }
        }
        __syncthreads();   // hscr complete; smem h image dead
        if (tid < 64) {    // block's 1KB region: 16 full-line WT stores + drain + post
            u32x4 v = *(const u32x4*)(hscr + tid * 8);
            store_16B_wt((char*)h_lstm
                         + (size_t)((dir * 2 + ((t + 1) & 1)) * 2 + rh) * 65536
                         + (size_t)(cg * 64 + tid) * 16, v);
            asm volatile("s_waitcnt vmcnt(0)" ::: "memory");
            if (tid == 0)
                __hip_atomic_store(flags + dir * 128 + rh * 64 + cg, (unsigned)(t + 1),
                                   __ATOMIC_RELAXED, __HIP_MEMORY_SCOPE_AGENT);
        }
    }

    // =============== attention finalize ===============
    flag_barrier(flags, 256, 256, 256 + bid, 2u);   // heavy: att_part cached-written
    {
        int i = tid & 127, half = tid >> 7;          // half = dir
        int item = bid * 128 + i;                    // 32768 = 512 t x 64 rows
        int tt = item >> 6, grow = item & 63;
        int rl = grow & 31, rh2 = grow >> 5;
        float s = 0.f;
        const float* p = att_part + (size_t)((half + rh2 * 2) * 2) * 16384
                         + (size_t)tt * 32 + rl;
        for (int cgi = 0; cgi < 64; ++cgi) {
            size_t off = (size_t)cgi * 8 * 16384;    // slot stride per cg = 8
            s += p[off] + p[off + 16384];            // nc = 0, 1
        }
        float* red = (float*)dumpbase;
        if (half) red[i] = s;
        __syncthreads();
        if (!half)
            out[BATCH * COUT + grow * SEQ + tt] = sigm(ATT_SIG_W * (s + red[i] + att_fc_b[0]));
    }
    flag_barrier(flags, 256, 256, 256 + bid, 3u);   // heavy: att out cached-written
    if (bid >= 128) return;

    // =============== TAGM loop (128 blocks: rh = bid&1, cg = bid>>1) ===============
    int rhT = bid & 1, cgT = bid >> 1;
    int mhT = (wave >> 1) & 1;                       // kh reused
    bf16x8 wt[20];
    {
        const unsigned short* wp = Wtp + (size_t)(cgT * 2 + kh) * 10240;
#pragma unroll
        for (int f = 0; f < 20; ++f)
            wt[f] = *(const bf16x8*)(wp + f * 512 + lane * 8);
    }
    int colT = cgT * 16 + c15;
    float bbT = i2h_b[colT] + h2h_b[colT];
    for (int i = tid; i < 512; i += 256) auxf[i] = 0.f;   // h master [32][16]
    __syncthreads();
    const float* attd = out + BATCH * COUT;

    for (int t = 0; t < SEQ; ++t) {
        const unsigned short* xrow = xt + (size_t)t * BATCH * DIM;
        bf16x8 xa[8];
        if (kh == 0) {
#pragma unroll
            for (int ksl = 0; ksl < 8; ++ksl) {
                int row = rhT * 32 + mhT * 16 + c15;
                xa[ksl] = *(const bf16x8*)(xrow + row * DIM + ksl * 32 + q * 8);
            }
        }
        if (t > 0) {
            for (;;) {
                bool ok = true;
                if (lane < 16)
                    ok = (__hip_atomic_load(flags + 512 + rhT * 64 + wave * 16 + lane,
                                            __ATOMIC_RELAXED,
                                            __HIP_MEMORY_SCOPE_AGENT) >= (unsigned)t);
                if (__all(ok)) break;
                __builtin_amdgcn_s_sleep(1);
            }
        }
        __builtin_amdgcn_sched_barrier(0);
        {
            const char* hsrc = (const char*)h_tagm + (size_t)((t & 1) * 2 + rhT) * 65536;
            char* lbase = smem + (size_t)wave * 16384 + (size_t)lane * 16;
#pragma unroll
            for (int i = 0; i < 16; ++i) {
                int s = wave * 1024 + i * 64 + lane;
                GLOAD_LDS_COHERENT(hsrc + (size_t)s * 16, lbase + (size_t)i * 1024);
            }
        }
        __syncthreads();
        f32x4 acc = {};
#pragma unroll
        for (int ksl = 0; ksl < 20; ++ksl) {
            bf16x8 a;
            if (kh == 0 && ksl < 8) {
                a = xa[ksl];
            } else {
                int kcol = kh * 640 + ksl * 32 + q * 8 - 256;
                a = *(const bf16x8*)(smem + (size_t)(kcol >> 4) * 1024
                                     + (size_t)((kcol >> 3) & 1) * 512
                                     + (size_t)(mhT * 16 + c15) * 16);
            }
            acc = __builtin_amdgcn_mfma_f32_16x16x32_bf16(a, wt[ksl], acc, 0, 0, 0);
        }
        if (kh == 1)
            *(f32x4*)(dumpbase + mhT * 1024 + lane * 16) = acc;
        __syncthreads();
        if (kh == 0) {
            f32x4 g = acc + *(const f32x4*)(dumpbase + mhT * 1024 + lane * 16);
#pragma unroll
            for (int r = 0; r < 4; ++r) {
                int rl = mhT * 16 + q * 4 + r;
                float cand = g[r] + bbT;
                cand = cand > 0.f ? cand : 0.f;
                float a = attd[(rhT * 32 + rl) * SEQ + t];
                float hold = auxf[rl * 16 + c15];
                float hn = a * cand + (1.f - a) * hold;
                auxf[rl * 16 + c15] = hn;
                hscr[(c15 >> 3) * 256 + rl * 8 + (c15 & 7)] = f2bf(hn);
            }
        }
        __syncthreads();
        if (tid < 64) {
            u32x4 v = *(const u32x4*)(hscr + tid * 8);
            store_16B_wt((char*)h_tagm + (size_t)((((t + 1) & 1)) * 2 + rhT) * 65536
                         + (size_t)(cgT * 64 + tid) * 16, v);
            asm volatile("s_waitcnt vmcnt(0)" ::: "memory");
            if (tid == 0)
                __hip_atomic_store(flags + 512 + rhT * 64 + cgT, (unsigned)(t + 1),
                                   __ATOMIC_RELAXED, __HIP_MEMORY_SCOPE_AGENT);
        }
    }

    // dump final h (f32) for FC
    for (int i = tid; i < 512; i += 256) {
        int rl = i >> 4, cl = i & 15;
        h_f32[(size_t)(rhT * 32 + rl) * HID + cgT * 16 + cl] = auxf[i];
    }
    flag_barrier(flags, 704, 128, 704 + bid, 1u);   // heavy: h_f32 cached-written
    if (bid >= 64) return;

    // =============== FC: out[b][c], block = batch row ===============
    {
        float* fcp = (float*)dumpbase;   // [2][128]
        int c = tid & 127, half = tid >> 7;
        const float* hrow = h_f32 + (size_t)bid * HID;
        float s = 0.f;
        for (int k = half * 512; k < half * 512 + 512; ++k)
            s += hrow[k] * fc_w[(size_t)k * COUT + c];
        fcp[half * 128 + c] = s;
        __syncthreads();
        if (tid < 128)
            out[bid * COUT + tid] = fcp[tid] + fcp[128 + tid] + fc_b[tid];
    }
}

extern "C" void kernel_launch(void* const* d_in, const int* in_sizes, int n_in,
                              void* d_out, int out_size, void* d_ws, size_t ws_size,
                              hipStream_t stream) {
    const float* x          = (const float*)d_in[0];
    const float* i2h_w      = (const float*)d_in[1];
    const float* i2h_b      = (const float*)d_in[2];
    const float* h2h_w      = (const float*)d_in[3];
    const float* h2h_b      = (const float*)d_in[4];
    const float* fc_w       = (const float*)d_in[5];
    const float* fc_b       = (const float*)d_in[6];
    const float* att_wi_fwd = (const float*)d_in[7];
    const float* att_wh_fwd = (const float*)d_in[8];
    const float* att_b_fwd  = (const float*)d_in[9];
    const float* att_wi_bwd = (const float*)d_in[10];
    const float* att_wh_bwd = (const float*)d_in[11];
    const float* att_b_bwd  = (const float*)d_in[12];
    const float* att_fc_w   = (const float*)d_in[13];
    const float* att_fc_b   = (const float*)d_in[14];
    float* out = (float*)d_out;

    char* ws = (char*)d_ws;
    // setup-phase (dead after packs)
    unsigned short* WfT = (unsigned short*)(ws + 0);          // 10485760
    unsigned short* WbT = (unsigned short*)(ws + 10485760);   // 10485760
    unsigned short* WtT = (unsigned short*)(ws + 20971520);   // 2621440 -> 23592960
    // packed fragment weights
    unsigned short* Wfp = (unsigned short*)(ws + 23592960);   // 10485760
    unsigned short* Wbp = (unsigned short*)(ws + 34078720);   // 10485760 -> 44564480
    unsigned short* Wtp = (unsigned short*)(ws + 17829888);   // 2621440 -> 20451328 (survives)
    // runtime region
    unsigned short* xtb    = (unsigned short*)(ws + 0);        // 16777216
    unsigned short* h_lstm = (unsigned short*)(ws + 16777216); // 524288 (uses 512KB)
    unsigned short* h_tagm = (unsigned short*)(ws + 17301504); // 262144 (uses 256KB)
    float*          h_f32  = (float*)(ws + 17563648);          // 262144
    unsigned*       flags  = (unsigned*)(ws + 17825792);       // 4096 -> 17829888
    // att_part ALIASES Wfp/Wbp (weights register-resident after epoch-1 barrier)
    float*          att_part = (float*)(ws + 23592960);        // 512*16384*4 = 33554432

    transpose_weights<<<20 * (NGATE / 64), 256, 0, stream>>>(att_wi_fwd, att_wh_fwd, WfT, NGATE);
    transpose_weights<<<20 * (NGATE / 64), 256, 0, stream>>>(att_wi_bwd, att_wh_bwd, WbT, NGATE);
    transpose_weights<<<20 * (HID / 64), 256, 0, stream>>>(i2h_w, h2h_w, WtT, HID);
    pack_lstm<<<256, 256, 0, stream>>>(WfT, Wfp);
    pack_lstm<<<256, 256, 0, stream>>>(WbT, Wbp);
    pack_tagm<<<128, 256, 0, stream>>>(WtT, Wtp);
    transpose_x<<<(SEQ * BATCH * DIM + 255) / 256, 256, 0, stream>>>(x, xtb);
    // zero recurrent state + flags every call
    (void)hipMemsetAsync(ws + 16777216, 0, 17829888 - 16777216, stream);

    // 96KB LDS: forces 1 block/CU (78KB would allow 2/CU -> uneven packing)
    static const int SMEM_BYTES = 98304;
    (void)hipFuncSetAttribute(reinterpret_cast<const void*>(tagm_fused),
                              hipFuncAttributeMaxDynamicSharedMemorySize, SMEM_BYTES);
    tagm_fused<<<256, 256, SMEM_BYTES, stream>>>(
        xtb, Wfp, Wbp, Wtp, att_b_fwd, att_b_bwd, att_fc_w, att_fc_b,
        i2h_b, h2h_b, fc_w, fc_b, h_lstm, h_tagm, h_f32, att_part, flags, out);
}

// Round 14
// 6376.605 us; speedup vs baseline: 1.7032x; 1.0046x over previous
//
#include <hip/hip_runtime.h>
#include <hip/hip_bf16.h>
#include <cstdint>
#include <cstddef>

constexpr int BATCH = 64;
constexpr int SEQ   = 512;
constexpr int DIM   = 256;
constexpr int HID   = 1024;
constexpr int COUT  = 128;
constexpr int KTOT  = DIM + HID;   // 1280
constexpr int NGATE = 4 * HID;     // 4096
constexpr float ATT_SIG_W = 3.0f;

using bf16x8 = __attribute__((ext_vector_type(8))) __bf16;
using f32x4  = __attribute__((ext_vector_type(4))) float;
using u32x4  = __attribute__((ext_vector_type(4))) unsigned int;

__device__ __forceinline__ unsigned short f2bf(float f) {
    union { float f; unsigned u; } v; v.f = f;
    unsigned u = v.u;
    u += 0x7fffu + ((u >> 16) & 1u);
    return (unsigned short)(u >> 16);
}

__device__ __forceinline__ float sigm(float x) { return 1.f / (1.f + __expf(-x)); }

// 16B write-through store (sc0 sc1); payload must be ext_vector_type (reg quad)
__device__ __forceinline__ void store_16B_wt(void* p, u32x4 v) {
    asm volatile("global_store_dwordx4 %0, %1, off sc0 sc1"
                 :: "v"(p), "v"(v) : "memory");
}

// global->LDS direct copy, 16B/lane, sc0|sc1 (aux=17): bypass L1+L2, read coherent L3
#define GLOAD_LDS_COHERENT(gptr, lptr)                                     \
    __builtin_amdgcn_global_load_lds(                                      \
        (const __attribute__((address_space(1))) void*)(gptr),             \
        (__attribute__((address_space(3))) void*)(lptr), 16, 0, 17)

// ---- weight transpose+convert: out[n][k] = bf16( k<DIM ? wi[k][n] : wh[k-DIM][n] )
__global__ void transpose_weights(const float* __restrict__ wi,
                                  const float* __restrict__ wh,
                                  unsigned short* __restrict__ out, int N) {
    __shared__ float tile[64][65];
    int ntiles = N >> 6;
    int kt = blockIdx.x / ntiles;
    int nt = blockIdx.x % ntiles;
    int k0 = kt << 6, n0 = nt << 6;
    int a = threadIdx.x & 63, g = threadIdx.x >> 6;
#pragma unroll
    for (int p = 0; p < 16; ++p) {
        int kr = p * 4 + g;
        int k = k0 + kr;
        const float* src = (k < DIM) ? (wi + (size_t)k * N) : (wh + (size_t)(k - DIM) * N);
        tile[kr][a] = src[n0 + a];
    }
    __syncthreads();
#pragma unroll
    for (int p = 0; p < 16; ++p) {
        int nr = p * 4 + g;
        out[(size_t)(n0 + nr) * KTOT + (k0 + a)] = f2bf(tile[a][nr]);
    }
}

// ---- x [B][T][D] f32 -> xt [T][B][D] bf16
__global__ void transpose_x(const float* __restrict__ x, unsigned short* __restrict__ xt) {
    size_t idx = (size_t)blockIdx.x * blockDim.x + threadIdx.x;
    if (idx >= (size_t)SEQ * BATCH * DIM) return;
    int d = idx % DIM;
    size_t r = idx / DIM;
    int b = r % BATCH;
    int t = r / BATCH;
    xt[idx] = f2bf(x[((size_t)b * SEQ + t) * DIM + d]);
}

// ---- pack LSTM weights into per-(colgroup8, khalf) MFMA fragment order (unchanged)
__global__ void pack_lstm(const unsigned short* __restrict__ WT,
                          unsigned short* __restrict__ out) {
    int cg = blockIdx.x >> 1, kh = blockIdx.x & 1;
    size_t base = (size_t)blockIdx.x * 20480;
#pragma unroll
    for (int j = 0; j < 80; ++j) {
        int idx = threadIdx.x * 80 + j;
        int frag = idx >> 9;
        int rem = idx & 511;
        int lane = rem >> 3, e = rem & 7;
        int nt = frag / 20, ksl = frag % 20;
        int p = nt * 16 + (lane & 15);
        int origcol = (p >> 3) * 1024 + cg * 8 + (p & 7);
        int k = kh * 640 + ksl * 32 + ((lane >> 4) & 3) * 8 + e;
        out[base + idx] = WT[(size_t)origcol * KTOT + k];
    }
}

// ---- pack TAGM weights: region (cg16, kh): 20 frags x 1024B; col = cg*16+(lane&15)
__global__ void pack_tagm(const unsigned short* __restrict__ WT,
                          unsigned short* __restrict__ out) {
    int cg = blockIdx.x >> 1, kh = blockIdx.x & 1;
    size_t base = (size_t)blockIdx.x * 10240;
#pragma unroll
    for (int j = 0; j < 40; ++j) {
        int idx = threadIdx.x * 40 + j;
        int ksl = idx >> 9;
        int rem = idx & 511;
        int lane = rem >> 3, e = rem & 7;
        int origcol = cg * 16 + (lane & 15);
        int k = kh * 640 + ksl * 32 + ((lane >> 4) & 3) * 8 + e;
        out[base + idx] = WT[(size_t)origcol * KTOT + k];
    }
}

// ---- block-wide light barrier (weights epoch only)
__device__ __forceinline__ void flag_light(unsigned* flags, int base, int cnt,
                                           int myidx, unsigned epoch) {
    asm volatile("s_waitcnt vmcnt(0)" ::: "memory");
    __syncthreads();
    if (threadIdx.x == 0)
        __hip_atomic_store(flags + myidx, epoch, __ATOMIC_RELAXED, __HIP_MEMORY_SCOPE_AGENT);
    if (threadIdx.x < 64) {
        for (;;) {
            bool ok = true;
            for (int j = (int)threadIdx.x; j < cnt; j += 64)
                ok &= (__hip_atomic_load(flags + base + j, __ATOMIC_RELAXED,
                                         __HIP_MEMORY_SCOPE_AGENT) >= epoch);
            if (__all(ok)) break;
            __builtin_amdgcn_s_sleep(1);
        }
    }
    __syncthreads();
}

// ---- HEAVY barrier (phase boundaries only): full release/acquire fences
__device__ __forceinline__ void flag_barrier(unsigned* flags, int base, int cnt,
                                             int myidx, unsigned epoch) {
    __syncthreads();
    if (threadIdx.x == 0) {
        __builtin_amdgcn_fence(__ATOMIC_RELEASE, "agent");   // wbl2
        __hip_atomic_store(flags + myidx, epoch, __ATOMIC_RELAXED, __HIP_MEMORY_SCOPE_AGENT);
    }
    if (threadIdx.x < 64) {
        for (;;) {
            bool ok = true;
            for (int j = (int)threadIdx.x; j < cnt; j += 64)
                ok &= (__hip_atomic_load(flags + base + j, __ATOMIC_RELAXED,
                                         __HIP_MEMORY_SCOPE_AGENT) >= epoch);
            if (__all(ok)) break;
            __builtin_amdgcn_s_sleep(1);
        }
        if (threadIdx.x == 0)
            __builtin_amdgcn_fence(__ATOMIC_ACQUIRE, "agent");   // inv
    }
    __syncthreads();
}

// ======== persistent fused kernel ========
// 2-D split: LSTM block = (dir = bid&1, rh = (bid>>1)&1 : 32 batch rows,
// cg = bid>>2 : 16 h-cols). Stage = only its row-half's h = 64 KB (was 128):
// broadcast volume 32->16 MB/step. Wave = (nc = w>>1, kh = w&1): 32 packed
// gate-cols x 640 K in 160 VGPR (same as before), M=32, 80 MFMAs/wave.
// h layout [dir][buf][rh] 64KB: chunk s = cg*64 + ch*32 + row (ch = 8-col half
// of block's 16 cols) -> block writes contiguous 1KB; stage identity-coalesced;
// LDS frag read = (kcol>>4)*1024 + ((kcol>>3)&1)*512 + row*16 (16B stride, free).
// TAGM (bid<128): block = (rh = bid&1, cg = bid>>1 : 16 cols); wave = (mh, kh).
__global__ __launch_bounds__(256)
void tagm_fused(const unsigned short* __restrict__ xt,
                const unsigned short* __restrict__ Wfp,
                const unsigned short* __restrict__ Wbp,
                const unsigned short* __restrict__ Wtp,
                const float* __restrict__ bias_f, const float* __restrict__ bias_b,
                const float* __restrict__ attw, const float* __restrict__ att_fc_b,
                const float* __restrict__ i2h_b, const float* __restrict__ h2h_b,
                const float* __restrict__ fc_w, const float* __restrict__ fc_b,
                unsigned short* __restrict__ h_lstm,  // [2 dir][2 buf][2 rh] x 64KB
                unsigned short* __restrict__ h_tagm,  // [2 buf][2 rh] x 64KB
                float* __restrict__ h_f32,            // [64][1024]
                float* __restrict__ att_part,         // [512 slots][512t*32] f32 (aliases Wfp/Wbp!)
                unsigned* __restrict__ flags,         // [1024]
                float* __restrict__ out) {
    extern __shared__ char smem[];                   // [0,65536): blocked h image (row-half)
    char* dumpbase = smem + 65536;                   // 8 KB acc dump
    float* auxf = (float*)(smem + 65536 + 8192);     // 4 KB: LSTM c / TAGM h master
    unsigned short* hscr = (unsigned short*)(smem + 65536 + 8192 + 4096);  // 2 KB

    int tid = threadIdx.x;
    int wave = tid >> 6, lane = tid & 63;
    int bid = blockIdx.x;
    int dir = bid & 1, rh = (bid >> 1) & 1, cg = bid >> 2;   // cg in [0,64)
    int nc = wave >> 1, kh = wave & 1;
    int q = lane >> 4, c15 = lane & 15;
    int hc = lane & 7;

    // ---- LSTM weight fragments -> registers (region cg8 = cg*2+nc, khalf kh)
    bf16x8 wreg[40];
    {
        const unsigned short* wp = (dir ? Wbp : Wfp)
                                   + (size_t)((cg * 2 + nc) * 2 + kh) * 20480;
#pragma unroll
        for (int f = 0; f < 40; ++f)
            wreg[f] = *(const bf16x8*)(wp + f * 512 + lane * 8);
    }
    int colE = cg * 16 + nc * 8 + hc;
    const float* bias = dir ? bias_b : bias_f;
    float b_ii = bias[colE], b_ff = bias[HID + colE];
    float b_gg = bias[2 * HID + colE], b_oo = bias[3 * HID + colE];
    float attw_l = attw[dir * HID + colE];

    for (int i = tid; i < 512; i += 256) auxf[i] = 0.f;   // c-state [32 rows][16 cols]

    // weights in regs before att_part clobbers Wfp/Wbp
    flag_light(flags, 256, 256, 256 + bid, 1u);

    // =============== LSTM loop ===============
    for (int t = 0; t < SEQ; ++t) {
        int tx = dir ? (SEQ - 1 - t) : t;
        const unsigned short* xrow = xt + (size_t)tx * BATCH * DIM;
        bf16x8 xa[16];
        if (kh == 0) {
#pragma unroll
            for (int ksl = 0; ksl < 8; ++ksl)
#pragma unroll
                for (int mt = 0; mt < 2; ++mt) {
                    int row = rh * 32 + mt * 16 + c15;
                    xa[ksl * 2 + mt] = *(const bf16x8*)(xrow + row * DIM + ksl * 32 + q * 8);
                }
        }
        // per-wave: poll MY 16 producers of group (dir, rh), then stage their 16KB
        if (t > 0) {
            for (;;) {
                bool ok = true;
                if (lane < 16)
                    ok = (__hip_atomic_load(flags + dir * 128 + rh * 64 + wave * 16 + lane,
                                            __ATOMIC_RELAXED,
                                            __HIP_MEMORY_SCOPE_AGENT) >= (unsigned)t);
                if (__all(ok)) break;
                __builtin_amdgcn_s_sleep(1);
            }
        }
        __builtin_amdgcn_sched_barrier(0);   // don't hoist stage loads above poll
        {
            const char* hsrc = (const char*)h_lstm
                               + (size_t)((dir * 2 + (t & 1)) * 2 + rh) * 65536;
            char* lbase = smem + (size_t)wave * 16384 + (size_t)lane * 16;
#pragma unroll
            for (int i = 0; i < 16; ++i) {
                int s = wave * 1024 + i * 64 + lane;   // chunk index (identity image)
                GLOAD_LDS_COHERENT(hsrc + (size_t)s * 16, lbase + (size_t)i * 1024);
            }
        }
        __syncthreads();   // all quarters staged

        f32x4 acc[2][2] = {};
#pragma unroll
        for (int ksl = 0; ksl < 20; ++ksl) {
#pragma unroll
            for (int mt = 0; mt < 2; ++mt) {
                bf16x8 a;
                if (kh == 0 && ksl < 8) {
                    a = xa[ksl * 2 + mt];
                } else {
                    int kcol = kh * 640 + ksl * 32 + q * 8 - 256;   // h column 0..1023
                    a = *(const bf16x8*)(smem + (size_t)(kcol >> 4) * 1024
                                         + (size_t)((kcol >> 3) & 1) * 512
                                         + (size_t)(mt * 16 + c15) * 16);
                }
                acc[mt][0] = __builtin_amdgcn_mfma_f32_16x16x32_bf16(a, wreg[ksl],      acc[mt][0], 0, 0, 0);
                acc[mt][1] = __builtin_amdgcn_mfma_f32_16x16x32_bf16(a, wreg[20 + ksl], acc[mt][1], 0, 0, 0);
            }
        }
        if (kh == 1) {   // dump partials to slot nc
            float* dp = (float*)(dumpbase + nc * 4096);
#pragma unroll
            for (int mt = 0; mt < 2; ++mt)
#pragma unroll
                for (int nt = 0; nt < 2; ++nt)
                    *(f32x4*)(dp + ((mt * 2 + nt) * 64 + lane) * 4) = acc[mt][nt];
        }
        __syncthreads();
        if (kh == 0) {   // reduce + gates + state update (waves 0,2 in parallel)
            const float* dp = (const float*)(dumpbase + nc * 4096);
            bool low = (lane & 8) == 0;
#pragma unroll
            for (int mt = 0; mt < 2; ++mt) {
                f32x4 g0 = acc[mt][0] + *(const f32x4*)(dp + ((mt * 2 + 0) * 64 + lane) * 4);
                f32x4 g1 = acc[mt][1] + *(const f32x4*)(dp + ((mt * 2 + 1) * 64 + lane) * 4);
                f32x4 av4;
#pragma unroll
                for (int r = 0; r < 4; ++r) {
                    float fo0 = __shfl(g0[r], lane ^ 8);   // f gate from partner lane
                    float fo1 = __shfl(g1[r], lane ^ 8);   // o gate from partner lane
                    int rl = mt * 16 + q * 4 + r;          // local row 0..31
                    float si = sigm(g0[r] + b_ii);
                    float sf = sigm(fo0 + b_ff);
                    float tg = tanhf(g1[r] + b_gg);
                    float so = sigm(fo1 + b_oo);
                    float cprev = auxf[rl * 16 + nc * 8 + hc];
                    float cn = sf * cprev + si * tg;
                    float hn = so * tanhf(cn);
                    float av = low ? hn * attw_l : 0.f;
                    av += __shfl_xor(av, 1); av += __shfl_xor(av, 2); av += __shfl_xor(av, 4);
                    av4[r] = av;
                    if (low) {
                        auxf[rl * 16 + nc * 8 + hc] = cn;
                        hscr[nc * 256 + rl * 8 + hc] = f2bf(hn);   // [ch=nc][row][8col]
                    }
                }
                if (c15 == 0)
                    *(f32x4*)(att_part + (size_t)(bid * 2 + nc) * 16384
                              + (size_t)tx * 32 + (mt * 16 + q * 4)) = av4;
            }
        }
        __syncthreads();   // hscr complete; smem h image dead
        if (tid < 64) {    // block's 1KB region: 16 full-line WT stores + drain + post
            u32x4 v = *(const u32x4*)(hscr + tid * 8);
            store_16B_wt((char*)h_lstm
                         + (size_t)((dir * 2 + ((t + 1) & 1)) * 2 + rh) * 65536
                         + (size_t)(cg * 64 + tid) * 16, v);
            asm volatile("s_waitcnt vmcnt(0)" ::: "memory");
            if (tid == 0)
                __hip_atomic_store(flags + dir * 128 + rh * 64 + cg, (unsigned)(t + 1),
                                   __ATOMIC_RELAXED, __HIP_MEMORY_SCOPE_AGENT);
        }
    }

    // =============== attention finalize ===============
    flag_barrier(flags, 256, 256, 256 + bid, 2u);   // heavy: att_part cached-written
    {
        int i = tid & 127, half = tid >> 7;          // half = dir
        int item = bid * 128 + i;                    // 32768 = 512 t x 64 rows
        int tt = item >> 6, grow = item & 63;
        int rl = grow & 31, rh2 = grow >> 5;
        float s = 0.f;
        const float* p = att_part + (size_t)((half + rh2 * 2) * 2) * 16384
                         + (size_t)tt * 32 + rl;
        for (int cgi = 0; cgi < 64; ++cgi) {
            size_t off = (size_t)cgi * 8 * 16384;    // slot stride per cg = 8
            s += p[off] + p[off + 16384];            // nc = 0, 1
        }
        float* red = (float*)dumpbase;
        if (half) red[i] = s;
        __syncthreads();
        if (!half)
            out[BATCH * COUT + grow * SEQ + tt] = sigm(ATT_SIG_W * (s + red[i] + att_fc_b[0]));
    }
    flag_barrier(flags, 256, 256, 256 + bid, 3u);   // heavy: att out cached-written
    if (bid >= 128) return;

    // =============== TAGM loop (128 blocks: rh = bid&1, cg = bid>>1) ===============
    int rhT = bid & 1, cgT = bid >> 1;
    int mhT = (wave >> 1) & 1;                       // kh reused
    bf16x8 wt[20];
    {
        const unsigned short* wp = Wtp + (size_t)(cgT * 2 + kh) * 10240;
#pragma unroll
        for (int f = 0; f < 20; ++f)
            wt[f] = *(const bf16x8*)(wp + f * 512 + lane * 8);
    }
    int colT = cgT * 16 + c15;
    float bbT = i2h_b[colT] + h2h_b[colT];
    for (int i = tid; i < 512; i += 256) auxf[i] = 0.f;   // h master [32][16]
    __syncthreads();
    const float* attd = out + BATCH * COUT;

    for (int t = 0; t < SEQ; ++t) {
        const unsigned short* xrow = xt + (size_t)t * BATCH * DIM;
        bf16x8 xa[8];
        if (kh == 0) {
#pragma unroll
            for (int ksl = 0; ksl < 8; ++ksl) {
                int row = rhT * 32 + mhT * 16 + c15;
                xa[ksl] = *(const bf16x8*)(xrow + row * DIM + ksl * 32 + q * 8);
            }
        }
        if (t > 0) {
            for (;;) {
                bool ok = true;
                if (lane < 16)
                    ok = (__hip_atomic_load(flags + 512 + rhT * 64 + wave * 16 + lane,
                                            __ATOMIC_RELAXED,
                                            __HIP_MEMORY_SCOPE_AGENT) >= (unsigned)t);
                if (__all(ok)) break;
                __builtin_amdgcn_s_sleep(1);
            }
        }
        __builtin_amdgcn_sched_barrier(0);
        {
            const char* hsrc = (const char*)h_tagm + (size_t)((t & 1) * 2 + rhT) * 65536;
            char* lbase = smem + (size_t)wave * 16384 + (size_t)lane * 16;
#pragma unroll
            for (int i = 0; i < 16; ++i) {
                int s = wave * 1024 + i * 64 + lane;
                GLOAD_LDS_COHERENT(hsrc + (size_t)s * 16, lbase + (size_t)i * 1024);
            }
        }
        __syncthreads();
        f32x4 acc = {};
#pragma unroll
        for (int ksl = 0; ksl < 20; ++ksl) {
            bf16x8 a;
            if (kh == 0 && ksl < 8) {
                a = xa[ksl];
            } else {
                int kcol = kh * 640 + ksl * 32 + q * 8 - 256;
                a = *(const bf16x8*)(smem + (size_t)(kcol >> 4) * 1024
                                     + (size_t)((kcol >> 3) & 1) * 512
                                     + (size_t)(mhT * 16 + c15) * 16);
            }
            acc = __builtin_amdgcn_mfma_f32_16x16x32_bf16(a, wt[ksl], acc, 0, 0, 0);
        }
        if (kh == 1)
            *(f32x4*)(dumpbase + mhT * 1024 + lane * 16) = acc;
        __syncthreads();
        if (kh == 0) {
            f32x4 g = acc + *(const f32x4*)(dumpbase + mhT * 1024 + lane * 16);
#pragma unroll
            for (int r = 0; r < 4; ++r) {
                int rl = mhT * 16 + q * 4 + r;
                float cand = g[r] + bbT;
                cand = cand > 0.f ? cand : 0.f;
                float a = attd[(rhT * 32 + rl) * SEQ + t];
                float hold = auxf[rl * 16 + c15];
                float hn = a * cand + (1.f - a) * hold;
                auxf[rl * 16 + c15] = hn;
                hscr[(c15 >> 3) * 256 + rl * 8 + (c15 & 7)] = f2bf(hn);
            }
        }
        __syncthreads();
        if (tid < 64) {
            u32x4 v = *(const u32x4*)(hscr + tid * 8);
            store_16B_wt((char*)h_tagm + (size_t)((((t + 1) & 1)) * 2 + rhT) * 65536
                         + (size_t)(cgT * 64 + tid) * 16, v);
            asm volatile("s_waitcnt vmcnt(0)" ::: "memory");
            if (tid == 0)
                __hip_atomic_store(flags + 512 + rhT * 64 + cgT, (unsigned)(t + 1),
                                   __ATOMIC_RELAXED, __HIP_MEMORY_SCOPE_AGENT);
        }
    }

    // dump final h (f32) for FC
    for (int i = tid; i < 512; i += 256) {
        int rl = i >> 4, cl = i & 15;
        h_f32[(size_t)(rhT * 32 + rl) * HID + cgT * 16 + cl] = auxf[i];
    }
    flag_barrier(flags, 704, 128, 704 + bid, 1u);   // heavy: h_f32 cached-written
    if (bid >= 64) return;

    // =============== FC: out[b][c], block = batch row ===============
    {
        float* fcp = (float*)dumpbase;   // [2][128]
        int c = tid & 127, half = tid >> 7;
        const float* hrow = h_f32 + (size_t)bid * HID;
        float s = 0.f;
        for (int k = half * 512; k < half * 512 + 512; ++k)
            s += hrow[k] * fc_w[(size_t)k * COUT + c];
        fcp[half * 128 + c] = s;
        __syncthreads();
        if (tid < 128)
            out[bid * COUT + tid] = fcp[tid] + fcp[128 + tid] + fc_b[tid];
    }
}

extern "C" void kernel_launch(void* const* d_in, const int* in_sizes, int n_in,
                              void* d_out, int out_size, void* d_ws, size_t ws_size,
                              hipStream_t stream) {
    const float* x          = (const float*)d_in[0];
    const float* i2h_w      = (const float*)d_in[1];
    const float* i2h_b      = (const float*)d_in[2];
    const float* h2h_w      = (const float*)d_in[3];
    const float* h2h_b      = (const float*)d_in[4];
    const float* fc_w       = (const float*)d_in[5];
    const float* fc_b       = (const float*)d_in[6];
    const float* att_wi_fwd = (const float*)d_in[7];
    const float* att_wh_fwd = (const float*)d_in[8];
    const float* att_b_fwd  = (const float*)d_in[9];
    const float* att_wi_bwd = (const float*)d_in[10];
    const float* att_wh_bwd = (const float*)d_in[11];
    const float* att_b_bwd  = (const float*)d_in[12];
    const float* att_fc_w   = (const float*)d_in[13];
    const float* att_fc_b   = (const float*)d_in[14];
    float* out = (float*)d_out;

    char* ws = (char*)d_ws;
    // setup-phase (dead after packs)
    unsigned short* WfT = (unsigned short*)(ws + 0);          // 10485760
    unsigned short* WbT = (unsigned short*)(ws + 10485760);   // 10485760
    unsigned short* WtT = (unsigned short*)(ws + 20971520);   // 2621440 -> 23592960
    // packed fragment weights
    unsigned short* Wfp = (unsigned short*)(ws + 23592960);   // 10485760
    unsigned short* Wbp = (unsigned short*)(ws + 34078720);   // 10485760 -> 44564480
    unsigned short* Wtp = (unsigned short*)(ws + 17829888);   // 2621440 -> 20451328 (survives)
    // runtime region
    unsigned short* xtb    = (unsigned short*)(ws + 0);        // 16777216
    unsigned short* h_lstm = (unsigned short*)(ws + 16777216); // 524288 (uses 512KB)
    unsigned short* h_tagm = (unsigned short*)(ws + 17301504); // 262144 (uses 256KB)
    float*          h_f32  = (float*)(ws + 17563648);          // 262144
    unsigned*       flags  = (unsigned*)(ws + 17825792);       // 4096 -> 17829888
    // att_part ALIASES Wfp/Wbp (weights register-resident after epoch-1 barrier)
    float*          att_part = (float*)(ws + 23592960);        // 512*16384*4 = 33554432

    transpose_weights<<<20 * (NGATE / 64), 256, 0, stream>>>(att_wi_fwd, att_wh_fwd, WfT, NGATE);
    transpose_weights<<<20 * (NGATE / 64), 256, 0, stream>>>(att_wi_bwd, att_wh_bwd, WbT, NGATE);
    transpose_weights<<<20 * (HID / 64), 256, 0, stream>>>(i2h_w, h2h_w, WtT, HID);
    pack_lstm<<<256, 256, 0, stream>>>(WfT, Wfp);
    pack_lstm<<<256, 256, 0, stream>>>(WbT, Wbp);
    pack_tagm<<<128, 256, 0, stream>>>(WtT, Wtp);
    transpose_x<<<(SEQ * BATCH * DIM + 255) / 256, 256, 0, stream>>>(x, xtb);
    // zero recurrent state + flags every call
    (void)hipMemsetAsync(ws + 16777216, 0, 17829888 - 16777216, stream);

    // 96KB LDS: forces 1 block/CU (78KB would allow 2/CU -> uneven packing)
    static const int SMEM_BYTES = 98304;
    (void)hipFuncSetAttribute(reinterpret_cast<const void*>(tagm_fused),
                              hipFuncAttributeMaxDynamicSharedMemorySize, SMEM_BYTES);
    tagm_fused<<<256, 256, SMEM_BYTES, stream>>>(
        xtb, Wfp, Wbp, Wtp, att_b_fwd, att_b_bwd, att_fc_w, att_fc_b,
        i2h_b, h2h_b, fc_w, fc_b, h_lstm, h_tagm, h_f32, att_part, flags, out);
}

// Round 15
// 6219.249 us; speedup vs baseline: 1.7463x; 1.0253x over previous
//
#include <hip/hip_runtime.h>
#include <hip/hip_bf16.h>
#include <cstdint>
#include <cstddef>

constexpr int BATCH = 64;
constexpr int SEQ   = 512;
constexpr int DIM   = 256;
constexpr int HID   = 1024;
constexpr int COUT  = 128;
constexpr int KTOT  = DIM + HID;   // 1280
constexpr int NGATE = 4 * HID;     // 4096
constexpr float ATT_SIG_W = 3.0f;

using bf16x8 = __attribute__((ext_vector_type(8))) __bf16;
using f32x4  = __attribute__((ext_vector_type(4))) float;
using u32x4  = __attribute__((ext_vector_type(4))) unsigned int;

__device__ __forceinline__ unsigned short f2bf(float f) {
    union { float f; unsigned u; } v; v.f = f;
    unsigned u = v.u;
    u += 0x7fffu + ((u >> 16) & 1u);
    return (unsigned short)(u >> 16);
}

__device__ __forceinline__ float sigm(float x) { return 1.f / (1.f + __expf(-x)); }

// 16B write-through store (sc0 sc1); payload must be ext_vector_type (reg quad)
__device__ __forceinline__ void store_16B_wt(void* p, u32x4 v) {
    asm volatile("global_store_dwordx4 %0, %1, off sc0 sc1"
                 :: "v"(p), "v"(v) : "memory");
}

// global->LDS direct copy, 16B/lane, sc0|sc1 (aux=17): bypass L1+L2, read coherent L3
#define GLOAD_LDS_COHERENT(gptr, lptr)                                     \
    __builtin_amdgcn_global_load_lds(                                      \
        (const __attribute__((address_space(1))) void*)(gptr),             \
        (__attribute__((address_space(3))) void*)(lptr), 16, 0, 17)

// ---- weight transpose+convert: out[n][k] = bf16( k<DIM ? wi[k][n] : wh[k-DIM][n] )
__global__ void transpose_weights(const float* __restrict__ wi,
                                  const float* __restrict__ wh,
                                  unsigned short* __restrict__ out, int N) {
    __shared__ float tile[64][65];
    int ntiles = N >> 6;
    int kt = blockIdx.x / ntiles;
    int nt = blockIdx.x % ntiles;
    int k0 = kt << 6, n0 = nt << 6;
    int a = threadIdx.x & 63, g = threadIdx.x >> 6;
#pragma unroll
    for (int p = 0; p < 16; ++p) {
        int kr = p * 4 + g;
        int k = k0 + kr;
        const float* src = (k < DIM) ? (wi + (size_t)k * N) : (wh + (size_t)(k - DIM) * N);
        tile[kr][a] = src[n0 + a];
    }
    __syncthreads();
#pragma unroll
    for (int p = 0; p < 16; ++p) {
        int nr = p * 4 + g;
        out[(size_t)(n0 + nr) * KTOT + (k0 + a)] = f2bf(tile[a][nr]);
    }
}

// ---- x [B][T][D] f32 -> xt [T][B][D] bf16
__global__ void transpose_x(const float* __restrict__ x, unsigned short* __restrict__ xt) {
    size_t idx = (size_t)blockIdx.x * blockDim.x + threadIdx.x;
    if (idx >= (size_t)SEQ * BATCH * DIM) return;
    int d = idx % DIM;
    size_t r = idx / DIM;
    int b = r % BATCH;
    int t = r / BATCH;
    xt[idx] = f2bf(x[((size_t)b * SEQ + t) * DIM + d]);
}

// ---- pack LSTM weights into per-(colgroup8, khalf) MFMA fragment order (unchanged)
__global__ void pack_lstm(const unsigned short* __restrict__ WT,
                          unsigned short* __restrict__ out) {
    int cg = blockIdx.x >> 1, kh = blockIdx.x & 1;
    size_t base = (size_t)blockIdx.x * 20480;
#pragma unroll
    for (int j = 0; j < 80; ++j) {
        int idx = threadIdx.x * 80 + j;
        int frag = idx >> 9;
        int rem = idx & 511;
        int lane = rem >> 3, e = rem & 7;
        int nt = frag / 20, ksl = frag % 20;
        int p = nt * 16 + (lane & 15);
        int origcol = (p >> 3) * 1024 + cg * 8 + (p & 7);
        int k = kh * 640 + ksl * 32 + ((lane >> 4) & 3) * 8 + e;
        out[base + idx] = WT[(size_t)origcol * KTOT + k];
    }
}

// ---- pack TAGM weights: region (cg16, kq): 10 frags x 1024B; col = cg*16+(lane&15),
// k = kq*320 + ksl*32 + q*8 + e  (K-quarter per wave)
__global__ void pack_tagm(const unsigned short* __restrict__ WT,
                          unsigned short* __restrict__ out) {
    int cg = blockIdx.x >> 2, kq = blockIdx.x & 3;
    size_t base = (size_t)blockIdx.x * 5120;
#pragma unroll
    for (int j = 0; j < 20; ++j) {
        int idx = threadIdx.x * 20 + j;
        int ksl = idx >> 9;
        int rem = idx & 511;
        int lane = rem >> 3, e = rem & 7;
        int origcol = cg * 16 + (lane & 15);
        int k = kq * 320 + ksl * 32 + ((lane >> 4) & 3) * 8 + e;
        out[base + idx] = WT[(size_t)origcol * KTOT + k];
    }
}

// ---- block-wide light barrier (weights epoch only)
__device__ __forceinline__ void flag_light(unsigned* flags, int base, int cnt,
                                           int myidx, unsigned epoch) {
    asm volatile("s_waitcnt vmcnt(0)" ::: "memory");
    __syncthreads();
    if (threadIdx.x == 0)
        __hip_atomic_store(flags + myidx, epoch, __ATOMIC_RELAXED, __HIP_MEMORY_SCOPE_AGENT);
    if (threadIdx.x < 64) {
        for (;;) {
            bool ok = true;
            for (int j = (int)threadIdx.x; j < cnt; j += 64)
                ok &= (__hip_atomic_load(flags + base + j, __ATOMIC_RELAXED,
                                         __HIP_MEMORY_SCOPE_AGENT) >= epoch);
            if (__all(ok)) break;
            __builtin_amdgcn_s_sleep(1);
        }
    }
    __syncthreads();
}

// ---- HEAVY barrier (phase boundaries only): full release/acquire fences
__device__ __forceinline__ void flag_barrier(unsigned* flags, int base, int cnt,
                                             int myidx, unsigned epoch) {
    __syncthreads();
    if (threadIdx.x == 0) {
        __builtin_amdgcn_fence(__ATOMIC_RELEASE, "agent");   // wbl2
        __hip_atomic_store(flags + myidx, epoch, __ATOMIC_RELAXED, __HIP_MEMORY_SCOPE_AGENT);
    }
    if (threadIdx.x < 64) {
        for (;;) {
            bool ok = true;
            for (int j = (int)threadIdx.x; j < cnt; j += 64)
                ok &= (__hip_atomic_load(flags + base + j, __ATOMIC_RELAXED,
                                         __HIP_MEMORY_SCOPE_AGENT) >= epoch);
            if (__all(ok)) break;
            __builtin_amdgcn_s_sleep(1);
        }
        if (threadIdx.x == 0)
            __builtin_amdgcn_fence(__ATOMIC_ACQUIRE, "agent");   // inv
    }
    __syncthreads();
}

// ======== persistent fused kernel ========
// LSTM (unchanged from R13): block = (dir, rh: 32 rows, cg: 16 cols); stage 64KB.
// TAGM (NEW): ALL 256 blocks = (rq = bid&3 : 16 rows, cgT = bid>>2 : 16 cols);
// wave kq = K-quarter (320). Stage = rq's h only = 32KB; M=16; waves 1-3 dump
// partials, wave 0 reduces + gates; 512B h write = 8 full lines.
__global__ __launch_bounds__(256)
void tagm_fused(const unsigned short* __restrict__ xt,
                const unsigned short* __restrict__ Wfp,
                const unsigned short* __restrict__ Wbp,
                const unsigned short* __restrict__ Wtp,
                const float* __restrict__ bias_f, const float* __restrict__ bias_b,
                const float* __restrict__ attw, const float* __restrict__ att_fc_b,
                const float* __restrict__ i2h_b, const float* __restrict__ h2h_b,
                const float* __restrict__ fc_w, const float* __restrict__ fc_b,
                unsigned short* __restrict__ h_lstm,  // [2 dir][2 buf][2 rh] x 64KB
                unsigned short* __restrict__ h_tagm,  // [2 buf][4 rq] x 32KB
                float* __restrict__ h_f32,            // [64][1024]
                float* __restrict__ att_part,         // [512 slots][512t*32] f32 (aliases Wfp/Wbp!)
                unsigned* __restrict__ flags,         // [1024]
                float* __restrict__ out) {
    extern __shared__ char smem[];                   // [0,65536): blocked h image
    char* dumpbase = smem + 65536;                   // 8 KB acc dump
    float* auxf = (float*)(smem + 65536 + 8192);     // 4 KB: LSTM c / TAGM h master
    unsigned short* hscr = (unsigned short*)(smem + 65536 + 8192 + 4096);  // 2 KB

    int tid = threadIdx.x;
    int wave = tid >> 6, lane = tid & 63;
    int bid = blockIdx.x;
    int dir = bid & 1, rh = (bid >> 1) & 1, cg = bid >> 2;   // cg in [0,64)
    int nc = wave >> 1, kh = wave & 1;
    int q = lane >> 4, c15 = lane & 15;
    int hc = lane & 7;

    // ---- LSTM weight fragments -> registers (region cg8 = cg*2+nc, khalf kh)
    bf16x8 wreg[40];
    {
        const unsigned short* wp = (dir ? Wbp : Wfp)
                                   + (size_t)((cg * 2 + nc) * 2 + kh) * 20480;
#pragma unroll
        for (int f = 0; f < 40; ++f)
            wreg[f] = *(const bf16x8*)(wp + f * 512 + lane * 8);
    }
    int colE = cg * 16 + nc * 8 + hc;
    const float* bias = dir ? bias_b : bias_f;
    float b_ii = bias[colE], b_ff = bias[HID + colE];
    float b_gg = bias[2 * HID + colE], b_oo = bias[3 * HID + colE];
    float attw_l = attw[dir * HID + colE];

    for (int i = tid; i < 512; i += 256) auxf[i] = 0.f;   // c-state [32 rows][16 cols]

    // weights in regs before att_part clobbers Wfp/Wbp
    flag_light(flags, 256, 256, 256 + bid, 1u);

    // =============== LSTM loop (unchanged) ===============
    for (int t = 0; t < SEQ; ++t) {
        int tx = dir ? (SEQ - 1 - t) : t;
        const unsigned short* xrow = xt + (size_t)tx * BATCH * DIM;
        bf16x8 xa[16];
        if (kh == 0) {
#pragma unroll
            for (int ksl = 0; ksl < 8; ++ksl)
#pragma unroll
                for (int mt = 0; mt < 2; ++mt) {
                    int row = rh * 32 + mt * 16 + c15;
                    xa[ksl * 2 + mt] = *(const bf16x8*)(xrow + row * DIM + ksl * 32 + q * 8);
                }
        }
        if (t > 0) {
            for (;;) {
                bool ok = true;
                if (lane < 16)
                    ok = (__hip_atomic_load(flags + dir * 128 + rh * 64 + wave * 16 + lane,
                                            __ATOMIC_RELAXED,
                                            __HIP_MEMORY_SCOPE_AGENT) >= (unsigned)t);
                if (__all(ok)) break;
                __builtin_amdgcn_s_sleep(1);
            }
        }
        __builtin_amdgcn_sched_barrier(0);   // don't hoist stage loads above poll
        {
            const char* hsrc = (const char*)h_lstm
                               + (size_t)((dir * 2 + (t & 1)) * 2 + rh) * 65536;
            char* lbase = smem + (size_t)wave * 16384 + (size_t)lane * 16;
#pragma unroll
            for (int i = 0; i < 16; ++i) {
                int s = wave * 1024 + i * 64 + lane;   // chunk index (identity image)
                GLOAD_LDS_COHERENT(hsrc + (size_t)s * 16, lbase + (size_t)i * 1024);
            }
        }
        __syncthreads();   // all quarters staged

        f32x4 acc[2][2] = {};
#pragma unroll
        for (int ksl = 0; ksl < 20; ++ksl) {
#pragma unroll
            for (int mt = 0; mt < 2; ++mt) {
                bf16x8 a;
                if (kh == 0 && ksl < 8) {
                    a = xa[ksl * 2 + mt];
                } else {
                    int kcol = kh * 640 + ksl * 32 + q * 8 - 256;   // h column 0..1023
                    a = *(const bf16x8*)(smem + (size_t)(kcol >> 4) * 1024
                                         + (size_t)((kcol >> 3) & 1) * 512
                                         + (size_t)(mt * 16 + c15) * 16);
                }
                acc[mt][0] = __builtin_amdgcn_mfma_f32_16x16x32_bf16(a, wreg[ksl],      acc[mt][0], 0, 0, 0);
                acc[mt][1] = __builtin_amdgcn_mfma_f32_16x16x32_bf16(a, wreg[20 + ksl], acc[mt][1], 0, 0, 0);
            }
        }
        if (kh == 1) {   // dump partials to slot nc
            float* dp = (float*)(dumpbase + nc * 4096);
#pragma unroll
            for (int mt = 0; mt < 2; ++mt)
#pragma unroll
                for (int nt = 0; nt < 2; ++nt)
                    *(f32x4*)(dp + ((mt * 2 + nt) * 64 + lane) * 4) = acc[mt][nt];
        }
        __syncthreads();
        if (kh == 0) {   // reduce + gates + state update (waves 0,2 in parallel)
            const float* dp = (const float*)(dumpbase + nc * 4096);
            bool low = (lane & 8) == 0;
#pragma unroll
            for (int mt = 0; mt < 2; ++mt) {
                f32x4 g0 = acc[mt][0] + *(const f32x4*)(dp + ((mt * 2 + 0) * 64 + lane) * 4);
                f32x4 g1 = acc[mt][1] + *(const f32x4*)(dp + ((mt * 2 + 1) * 64 + lane) * 4);
                f32x4 av4;
#pragma unroll
                for (int r = 0; r < 4; ++r) {
                    float fo0 = __shfl(g0[r], lane ^ 8);   // f gate from partner lane
                    float fo1 = __shfl(g1[r], lane ^ 8);   // o gate from partner lane
                    int rl = mt * 16 + q * 4 + r;          // local row 0..31
                    float si = sigm(g0[r] + b_ii);
                    float sf = sigm(fo0 + b_ff);
                    float tg = tanhf(g1[r] + b_gg);
                    float so = sigm(fo1 + b_oo);
                    float cprev = auxf[rl * 16 + nc * 8 + hc];
                    float cn = sf * cprev + si * tg;
                    float hn = so * tanhf(cn);
                    float av = low ? hn * attw_l : 0.f;
                    av += __shfl_xor(av, 1); av += __shfl_xor(av, 2); av += __shfl_xor(av, 4);
                    av4[r] = av;
                    if (low) {
                        auxf[rl * 16 + nc * 8 + hc] = cn;
                        hscr[nc * 256 + rl * 8 + hc] = f2bf(hn);   // [ch=nc][row][8col]
                    }
                }
                if (c15 == 0)
                    *(f32x4*)(att_part + (size_t)(bid * 2 + nc) * 16384
                              + (size_t)tx * 32 + (mt * 16 + q * 4)) = av4;
            }
        }
        __syncthreads();   // hscr complete; smem h image dead
        if (tid < 64) {    // block's 1KB region: 16 full-line WT stores + drain + post
            u32x4 v = *(const u32x4*)(hscr + tid * 8);
            store_16B_wt((char*)h_lstm
                         + (size_t)((dir * 2 + ((t + 1) & 1)) * 2 + rh) * 65536
                         + (size_t)(cg * 64 + tid) * 16, v);
            asm volatile("s_waitcnt vmcnt(0)" ::: "memory");
            if (tid == 0)
                __hip_atomic_store(flags + dir * 128 + rh * 64 + cg, (unsigned)(t + 1),
                                   __ATOMIC_RELAXED, __HIP_MEMORY_SCOPE_AGENT);
        }
    }

    // =============== attention finalize ===============
    flag_barrier(flags, 256, 256, 256 + bid, 2u);   // heavy: att_part cached-written
    {
        int i = tid & 127, half = tid >> 7;          // half = dir
        int item = bid * 128 + i;                    // 32768 = 512 t x 64 rows
        int tt = item >> 6, grow = item & 63;
        int rl = grow & 31, rh2 = grow >> 5;
        float s = 0.f;
        const float* p = att_part + (size_t)((half + rh2 * 2) * 2) * 16384
                         + (size_t)tt * 32 + rl;
        for (int cgi = 0; cgi < 64; ++cgi) {
            size_t off = (size_t)cgi * 8 * 16384;    // slot stride per cg = 8
            s += p[off] + p[off + 16384];            // nc = 0, 1
        }
        float* red = (float*)dumpbase;
        if (half) red[i] = s;
        __syncthreads();
        if (!half)
            out[BATCH * COUT + grow * SEQ + tt] = sigm(ATT_SIG_W * (s + red[i] + att_fc_b[0]));
    }
    flag_barrier(flags, 256, 256, 256 + bid, 3u);   // heavy: att out cached-written

    // =============== TAGM loop (ALL 256 blocks: rq = bid&3, cgT = bid>>2) ===============
    int rq = bid & 3, cgT = bid >> 2;
    int kq = wave;                                    // K-quarter 0..3
    bf16x8 wt[10];
    {
        const unsigned short* wp = Wtp + (size_t)(cgT * 4 + kq) * 5120;
#pragma unroll
        for (int f = 0; f < 10; ++f)
            wt[f] = *(const bf16x8*)(wp + f * 512 + lane * 8);
    }
    int colT = cgT * 16 + c15;
    float bbT = i2h_b[colT] + h2h_b[colT];
    for (int i = tid; i < 256; i += 256) auxf[i] = 0.f;   // h master [16][16]
    __syncthreads();
    const float* attd = out + BATCH * COUT;

    for (int t = 0; t < SEQ; ++t) {
        bf16x8 xa[8];
        if (kq == 0) {
            const unsigned short* xrow = xt + (size_t)t * BATCH * DIM;
#pragma unroll
            for (int ksl = 0; ksl < 8; ++ksl) {
                int row = rq * 16 + c15;
                xa[ksl] = *(const bf16x8*)(xrow + row * DIM + ksl * 32 + q * 8);
            }
        }
        if (t > 0) {
            for (;;) {
                bool ok = true;
                if (lane < 16)
                    ok = (__hip_atomic_load(flags + 512 + rq * 64 + wave * 16 + lane,
                                            __ATOMIC_RELAXED,
                                            __HIP_MEMORY_SCOPE_AGENT) >= (unsigned)t);
                if (__all(ok)) break;
                __builtin_amdgcn_s_sleep(1);
            }
        }
        __builtin_amdgcn_sched_barrier(0);
        {   // stage rq's 32KB h image: identity linear copy, 8 chunks/thread
            const char* hsrc = (const char*)h_tagm + (size_t)((t & 1) * 4 + rq) * 32768;
            char* lbase = smem + (size_t)wave * 8192 + (size_t)lane * 16;
#pragma unroll
            for (int i = 0; i < 8; ++i) {
                int s = wave * 512 + i * 64 + lane;
                GLOAD_LDS_COHERENT(hsrc + (size_t)s * 16, lbase + (size_t)i * 1024);
            }
        }
        __syncthreads();
        f32x4 acc = {};
#pragma unroll
        for (int ksl = 0; ksl < 10; ++ksl) {
            bf16x8 a;
            if (kq == 0 && ksl < 8) {
                a = xa[ksl];
            } else {
                int kcol = kq * 320 + ksl * 32 + q * 8 - 256;   // h col 0..1023
                a = *(const bf16x8*)(smem + (size_t)(kcol >> 3) * 256
                                     + (size_t)c15 * 16);
            }
            acc = __builtin_amdgcn_mfma_f32_16x16x32_bf16(a, wt[ksl], acc, 0, 0, 0);
        }
        if (kq)   // waves 1-3 dump partials
            *(f32x4*)(dumpbase + (kq - 1) * 1024 + lane * 16) = acc;
        __syncthreads();
        if (kq == 0) {   // wave 0: reduce + gates (16 rows x 16 cols)
            f32x4 g = acc + *(const f32x4*)(dumpbase + lane * 16)
                          + *(const f32x4*)(dumpbase + 1024 + lane * 16)
                          + *(const f32x4*)(dumpbase + 2048 + lane * 16);
#pragma unroll
            for (int r = 0; r < 4; ++r) {
                int rl = q * 4 + r;
                float cand = g[r] + bbT;
                cand = cand > 0.f ? cand : 0.f;
                float a = attd[(rq * 16 + rl) * SEQ + t];
                float hold = auxf[rl * 16 + c15];
                float hn = a * cand + (1.f - a) * hold;
                auxf[rl * 16 + c15] = hn;
                hscr[(c15 >> 3) * 128 + rl * 8 + (c15 & 7)] = f2bf(hn);
            }
        }
        __syncthreads();
        if (tid < 32) {   // block's 512B region: 8 full lines + drain + post
            u32x4 v = *(const u32x4*)(hscr + tid * 8);
            store_16B_wt((char*)h_tagm + (size_t)((((t + 1) & 1)) * 4 + rq) * 32768
                         + (size_t)(cgT * 32 + tid) * 16, v);
            asm volatile("s_waitcnt vmcnt(0)" ::: "memory");
            if (tid == 0)
                __hip_atomic_store(flags + 512 + rq * 64 + cgT, (unsigned)(t + 1),
                                   __ATOMIC_RELAXED, __HIP_MEMORY_SCOPE_AGENT);
        }
    }

    // dump final h (f32) for FC
    for (int i = tid; i < 256; i += 256) {
        int rl = i >> 4, cl = i & 15;
        h_f32[(size_t)(rq * 16 + rl) * HID + cgT * 16 + cl] = auxf[i];
    }
    flag_barrier(flags, 768, 256, 768 + bid, 1u);   // heavy: h_f32 cached-written
    if (bid >= 64) return;

    // =============== FC: out[b][c], block = batch row ===============
    {
        float* fcp = (float*)dumpbase;   // [2][128]
        int c = tid & 127, half = tid >> 7;
        const float* hrow = h_f32 + (size_t)bid * HID;
        float s = 0.f;
        for (int k = half * 512; k < half * 512 + 512; ++k)
            s += hrow[k] * fc_w[(size_t)k * COUT + c];
        fcp[half * 128 + c] = s;
        __syncthreads();
        if (tid < 128)
            out[bid * COUT + tid] = fcp[tid] + fcp[128 + tid] + fc_b[tid];
    }
}

extern "C" void kernel_launch(void* const* d_in, const int* in_sizes, int n_in,
                              void* d_out, int out_size, void* d_ws, size_t ws_size,
                              hipStream_t stream) {
    const float* x          = (const float*)d_in[0];
    const float* i2h_w      = (const float*)d_in[1];
    const float* i2h_b      = (const float*)d_in[2];
    const float* h2h_w      = (const float*)d_in[3];
    const float* h2h_b      = (const float*)d_in[4];
    const float* fc_w       = (const float*)d_in[5];
    const float* fc_b       = (const float*)d_in[6];
    const float* att_wi_fwd = (const float*)d_in[7];
    const float* att_wh_fwd = (const float*)d_in[8];
    const float* att_b_fwd  = (const float*)d_in[9];
    const float* att_wi_bwd = (const float*)d_in[10];
    const float* att_wh_bwd = (const float*)d_in[11];
    const float* att_b_bwd  = (const float*)d_in[12];
    const float* att_fc_w   = (const float*)d_in[13];
    const float* att_fc_b   = (const float*)d_in[14];
    float* out = (float*)d_out;

    char* ws = (char*)d_ws;
    // setup-phase (dead after packs)
    unsigned short* WfT = (unsigned short*)(ws + 0);          // 10485760
    unsigned short* WbT = (unsigned short*)(ws + 10485760);   // 10485760
    unsigned short* WtT = (unsigned short*)(ws + 20971520);   // 2621440 -> 23592960
    // packed fragment weights
    unsigned short* Wfp = (unsigned short*)(ws + 23592960);   // 10485760
    unsigned short* Wbp = (unsigned short*)(ws + 34078720);   // 10485760 -> 44564480
    unsigned short* Wtp = (unsigned short*)(ws + 17829888);   // 2621440 -> 20451328 (survives)
    // runtime region
    unsigned short* xtb    = (unsigned short*)(ws + 0);        // 16777216
    unsigned short* h_lstm = (unsigned short*)(ws + 16777216); // 524288
    unsigned short* h_tagm = (unsigned short*)(ws + 17301504); // 262144
    float*          h_f32  = (float*)(ws + 17563648);          // 262144
    unsigned*       flags  = (unsigned*)(ws + 17825792);       // 4096 -> 17829888
    // att_part ALIASES Wfp/Wbp (weights register-resident after epoch-1 barrier)
    float*          att_part = (float*)(ws + 23592960);        // 512*16384*4 = 33554432

    transpose_weights<<<20 * (NGATE / 64), 256, 0, stream>>>(att_wi_fwd, att_wh_fwd, WfT, NGATE);
    transpose_weights<<<20 * (NGATE / 64), 256, 0, stream>>>(att_wi_bwd, att_wh_bwd, WbT, NGATE);
    transpose_weights<<<20 * (HID / 64), 256, 0, stream>>>(i2h_w, h2h_w, WtT, HID);
    pack_lstm<<<256, 256, 0, stream>>>(WfT, Wfp);
    pack_lstm<<<256, 256, 0, stream>>>(WbT, Wbp);
    pack_tagm<<<256, 256, 0, stream>>>(WtT, Wtp);
    transpose_x<<<(SEQ * BATCH * DIM + 255) / 256, 256, 0, stream>>>(x, xtb);
    // zero recurrent state + flags every call
    (void)hipMemsetAsync(ws + 16777216, 0, 17829888 - 16777216, stream);

    // 96KB LDS: forces 1 block/CU
    static const int SMEM_BYTES = 98304;
    (void)hipFuncSetAttribute(reinterpret_cast<const void*>(tagm_fused),
                              hipFuncAttributeMaxDynamicSharedMemorySize, SMEM_BYTES);
    tagm_fused<<<256, 256, SMEM_BYTES, stream>>>(
        xtb, Wfp, Wbp, Wtp, att_b_fwd, att_b_bwd, att_fc_w, att_fc_b,
        i2h_b, h2h_b, fc_w, fc_b, h_lstm, h_tagm, h_f32, att_part, flags, out);
}

// Round 16
// 6051.043 us; speedup vs baseline: 1.7949x; 1.0278x over previous
//
#include <hip/hip_runtime.h>
#include <hip/hip_bf16.h>
#include <cstdint>
#include <cstddef>

constexpr int BATCH = 64;
constexpr int SEQ   = 512;
constexpr int DIM   = 256;
constexpr int HID   = 1024;
constexpr int COUT  = 128;
constexpr int KTOT  = DIM + HID;   // 1280
constexpr int NGATE = 4 * HID;     // 4096
constexpr float ATT_SIG_W = 3.0f;

using bf16x8 = __attribute__((ext_vector_type(8))) __bf16;
using f32x4  = __attribute__((ext_vector_type(4))) float;
using u32x4  = __attribute__((ext_vector_type(4))) unsigned int;

__device__ __forceinline__ unsigned short f2bf(float f) {
    union { float f; unsigned u; } v; v.f = f;
    unsigned u = v.u;
    u += 0x7fffu + ((u >> 16) & 1u);
    return (unsigned short)(u >> 16);
}

__device__ __forceinline__ float sigm(float x) { return 1.f / (1.f + __expf(-x)); }

// 16B write-through store (sc0 sc1); payload must be ext_vector_type (reg quad)
__device__ __forceinline__ void store_16B_wt(void* p, u32x4 v) {
    asm volatile("global_store_dwordx4 %0, %1, off sc0 sc1"
                 :: "v"(p), "v"(v) : "memory");
}

// global->LDS direct copy, 16B/lane, sc0|sc1 (aux=17): bypass L1+L2, read coherent L3
#define GLOAD_LDS_COHERENT(gptr, lptr)                                     \
    __builtin_amdgcn_global_load_lds(                                      \
        (const __attribute__((address_space(1))) void*)(gptr),             \
        (__attribute__((address_space(3))) void*)(lptr), 16, 0, 17)

// ---- weight transpose+convert: out[n][k] = bf16( k<DIM ? wi[k][n] : wh[k-DIM][n] )
__global__ void transpose_weights(const float* __restrict__ wi,
                                  const float* __restrict__ wh,
                                  unsigned short* __restrict__ out, int N) {
    __shared__ float tile[64][65];
    int ntiles = N >> 6;
    int kt = blockIdx.x / ntiles;
    int nt = blockIdx.x % ntiles;
    int k0 = kt << 6, n0 = nt << 6;
    int a = threadIdx.x & 63, g = threadIdx.x >> 6;
#pragma unroll
    for (int p = 0; p < 16; ++p) {
        int kr = p * 4 + g;
        int k = k0 + kr;
        const float* src = (k < DIM) ? (wi + (size_t)k * N) : (wh + (size_t)(k - DIM) * N);
        tile[kr][a] = src[n0 + a];
    }
    __syncthreads();
#pragma unroll
    for (int p = 0; p < 16; ++p) {
        int nr = p * 4 + g;
        out[(size_t)(n0 + nr) * KTOT + (k0 + a)] = f2bf(tile[a][nr]);
    }
}

// ---- x [B][T][D] f32 -> xt [T][B][D] bf16
__global__ void transpose_x(const float* __restrict__ x, unsigned short* __restrict__ xt) {
    size_t idx = (size_t)blockIdx.x * blockDim.x + threadIdx.x;
    if (idx >= (size_t)SEQ * BATCH * DIM) return;
    int d = idx % DIM;
    size_t r = idx / DIM;
    int b = r % BATCH;
    int t = r / BATCH;
    xt[idx] = f2bf(x[((size_t)b * SEQ + t) * DIM + d]);
}

// ---- pack LSTM weights into per-(colgroup8, khalf) MFMA fragment order (unchanged)
__global__ void pack_lstm(const unsigned short* __restrict__ WT,
                          unsigned short* __restrict__ out) {
    int cg = blockIdx.x >> 1, kh = blockIdx.x & 1;
    size_t base = (size_t)blockIdx.x * 20480;
#pragma unroll
    for (int j = 0; j < 80; ++j) {
        int idx = threadIdx.x * 80 + j;
        int frag = idx >> 9;
        int rem = idx & 511;
        int lane = rem >> 3, e = rem & 7;
        int nt = frag / 20, ksl = frag % 20;
        int p = nt * 16 + (lane & 15);
        int origcol = (p >> 3) * 1024 + cg * 8 + (p & 7);
        int k = kh * 640 + ksl * 32 + ((lane >> 4) & 3) * 8 + e;
        out[base + idx] = WT[(size_t)origcol * KTOT + k];
    }
}

// ---- pack TAGM weights: region (cg16, kq): 10 frags x 1024B
__global__ void pack_tagm(const unsigned short* __restrict__ WT,
                          unsigned short* __restrict__ out) {
    int cg = blockIdx.x >> 2, kq = blockIdx.x & 3;
    size_t base = (size_t)blockIdx.x * 5120;
#pragma unroll
    for (int j = 0; j < 20; ++j) {
        int idx = threadIdx.x * 20 + j;
        int ksl = idx >> 9;
        int rem = idx & 511;
        int lane = rem >> 3, e = rem & 7;
        int origcol = cg * 16 + (lane & 15);
        int k = kq * 320 + ksl * 32 + ((lane >> 4) & 3) * 8 + e;
        out[base + idx] = WT[(size_t)origcol * KTOT + k];
    }
}

// ---- block-wide light barrier (weights epoch only)
__device__ __forceinline__ void flag_light(unsigned* flags, int base, int cnt,
                                           int myidx, unsigned epoch) {
    asm volatile("s_waitcnt vmcnt(0)" ::: "memory");
    __syncthreads();
    if (threadIdx.x == 0)
        __hip_atomic_store(flags + myidx, epoch, __ATOMIC_RELAXED, __HIP_MEMORY_SCOPE_AGENT);
    if (threadIdx.x < 64) {
        for (;;) {
            bool ok = true;
            for (int j = (int)threadIdx.x; j < cnt; j += 64)
                ok &= (__hip_atomic_load(flags + base + j, __ATOMIC_RELAXED,
                                         __HIP_MEMORY_SCOPE_AGENT) >= epoch);
            if (__all(ok)) break;
            __builtin_amdgcn_s_sleep(1);
        }
    }
    __syncthreads();
}

// ---- HEAVY barrier (phase boundaries only): full release/acquire fences
__device__ __forceinline__ void flag_barrier(unsigned* flags, int base, int cnt,
                                             int myidx, unsigned epoch) {
    __syncthreads();
    if (threadIdx.x == 0) {
        __builtin_amdgcn_fence(__ATOMIC_RELEASE, "agent");   // wbl2
        __hip_atomic_store(flags + myidx, epoch, __ATOMIC_RELAXED, __HIP_MEMORY_SCOPE_AGENT);
    }
    if (threadIdx.x < 64) {
        for (;;) {
            bool ok = true;
            for (int j = (int)threadIdx.x; j < cnt; j += 64)
                ok &= (__hip_atomic_load(flags + base + j, __ATOMIC_RELAXED,
                                         __HIP_MEMORY_SCOPE_AGENT) >= epoch);
            if (__all(ok)) break;
            __builtin_amdgcn_s_sleep(1);
        }
        if (threadIdx.x == 0)
            __builtin_amdgcn_fence(__ATOMIC_ACQUIRE, "agent");   // inv
    }
    __syncthreads();
}

// ======== persistent fused kernel ========
// R15 structure + chain-shortening: (1) x-MFMAs run BEFORE the stage barrier
// (xa issued before stage loads -> compiler waits vmcnt(16), overlapping MFMA
// with stage); (2) 4-way gates: each wave dumps the OTHER row-half's partials
// and computes gates for its own half (LSTM), / wave kq gates rows kq*4..+3
// (TAGM). Barrier count, layouts, flags unchanged.
__global__ __launch_bounds__(256)
void tagm_fused(const unsigned short* __restrict__ xt,
                const unsigned short* __restrict__ Wfp,
                const unsigned short* __restrict__ Wbp,
                const unsigned short* __restrict__ Wtp,
                const float* __restrict__ bias_f, const float* __restrict__ bias_b,
                const float* __restrict__ attw, const float* __restrict__ att_fc_b,
                const float* __restrict__ i2h_b, const float* __restrict__ h2h_b,
                const float* __restrict__ fc_w, const float* __restrict__ fc_b,
                unsigned short* __restrict__ h_lstm,  // [2 dir][2 buf][2 rh] x 64KB
                unsigned short* __restrict__ h_tagm,  // [2 buf][4 rq] x 32KB
                float* __restrict__ h_f32,            // [64][1024]
                float* __restrict__ att_part,         // [512 slots][512t*32] f32 (aliases Wfp/Wbp!)
                unsigned* __restrict__ flags,         // [1024]
                float* __restrict__ out) {
    extern __shared__ char smem[];                   // [0,65536): blocked h image
    char* dumpbase = smem + 65536;                   // 8 KB acc dump
    float* auxf = (float*)(smem + 65536 + 8192);     // 4 KB: LSTM c / TAGM h master
    unsigned short* hscr = (unsigned short*)(smem + 65536 + 8192 + 4096);  // 2 KB

    int tid = threadIdx.x;
    int wave = tid >> 6, lane = tid & 63;
    int bid = blockIdx.x;
    int dir = bid & 1, rh = (bid >> 1) & 1, cg = bid >> 2;   // cg in [0,64)
    int nc = wave >> 1, kh = wave & 1;
    int q = lane >> 4, c15 = lane & 15;
    int hc = lane & 7;

    // ---- LSTM weight fragments -> registers (region cg8 = cg*2+nc, khalf kh)
    bf16x8 wreg[40];
    {
        const unsigned short* wp = (dir ? Wbp : Wfp)
                                   + (size_t)((cg * 2 + nc) * 2 + kh) * 20480;
#pragma unroll
        for (int f = 0; f < 40; ++f)
            wreg[f] = *(const bf16x8*)(wp + f * 512 + lane * 8);
    }
    int colE = cg * 16 + nc * 8 + hc;
    const float* bias = dir ? bias_b : bias_f;
    float b_ii = bias[colE], b_ff = bias[HID + colE];
    float b_gg = bias[2 * HID + colE], b_oo = bias[3 * HID + colE];
    float attw_l = attw[dir * HID + colE];

    for (int i = tid; i < 512; i += 256) auxf[i] = 0.f;   // c-state [32 rows][16 cols]

    // weights in regs before att_part clobbers Wfp/Wbp
    flag_light(flags, 256, 256, 256 + bid, 1u);

    // =============== LSTM loop ===============
    for (int t = 0; t < SEQ; ++t) {
        int tx = dir ? (SEQ - 1 - t) : t;
        const unsigned short* xrow = xt + (size_t)tx * BATCH * DIM;
        bf16x8 xa[16];
        if (kh == 0) {
#pragma unroll
            for (int ksl = 0; ksl < 8; ++ksl)
#pragma unroll
                for (int mt = 0; mt < 2; ++mt) {
                    int row = rh * 32 + mt * 16 + c15;
                    xa[ksl * 2 + mt] = *(const bf16x8*)(xrow + row * DIM + ksl * 32 + q * 8);
                }
        }
        if (t > 0) {
            for (;;) {
                bool ok = true;
                if (lane < 16)
                    ok = (__hip_atomic_load(flags + dir * 128 + rh * 64 + wave * 16 + lane,
                                            __ATOMIC_RELAXED,
                                            __HIP_MEMORY_SCOPE_AGENT) >= (unsigned)t);
                if (__all(ok)) break;
                __builtin_amdgcn_s_sleep(1);
            }
        }
        __builtin_amdgcn_sched_barrier(0);   // don't hoist stage loads above poll
        {
            const char* hsrc = (const char*)h_lstm
                               + (size_t)((dir * 2 + (t & 1)) * 2 + rh) * 65536;
            char* lbase = smem + (size_t)wave * 16384 + (size_t)lane * 16;
#pragma unroll
            for (int i = 0; i < 16; ++i) {
                int s = wave * 1024 + i * 64 + lane;   // chunk index (identity image)
                GLOAD_LDS_COHERENT(hsrc + (size_t)s * 16, lbase + (size_t)i * 1024);
            }
        }
        f32x4 acc[2][2] = {};
        // x-MFMAs overlap the in-flight stage (xa is older than stage loads)
        if (kh == 0) {
#pragma unroll
            for (int ksl = 0; ksl < 8; ++ksl)
#pragma unroll
                for (int mt = 0; mt < 2; ++mt) {
                    acc[mt][0] = __builtin_amdgcn_mfma_f32_16x16x32_bf16(xa[ksl * 2 + mt], wreg[ksl],      acc[mt][0], 0, 0, 0);
                    acc[mt][1] = __builtin_amdgcn_mfma_f32_16x16x32_bf16(xa[ksl * 2 + mt], wreg[20 + ksl], acc[mt][1], 0, 0, 0);
                }
        }
        __syncthreads();   // all stage quarters landed

        if (kh == 0) {
#pragma unroll
            for (int ksl = 8; ksl < 20; ++ksl)
#pragma unroll
                for (int mt = 0; mt < 2; ++mt) {
                    int kcol = ksl * 32 + q * 8 - 256;             // [0,384)
                    bf16x8 a = *(const bf16x8*)(smem + (size_t)(kcol >> 4) * 1024
                                                + (size_t)((kcol >> 3) & 1) * 512
                                                + (size_t)(mt * 16 + c15) * 16);
                    acc[mt][0] = __builtin_amdgcn_mfma_f32_16x16x32_bf16(a, wreg[ksl],      acc[mt][0], 0, 0, 0);
                    acc[mt][1] = __builtin_amdgcn_mfma_f32_16x16x32_bf16(a, wreg[20 + ksl], acc[mt][1], 0, 0, 0);
                }
        } else {
#pragma unroll
            for (int ksl = 0; ksl < 20; ++ksl)
#pragma unroll
                for (int mt = 0; mt < 2; ++mt) {
                    int kcol = 384 + ksl * 32 + q * 8;             // [384,1024)
                    bf16x8 a = *(const bf16x8*)(smem + (size_t)(kcol >> 4) * 1024
                                                + (size_t)((kcol >> 3) & 1) * 512
                                                + (size_t)(mt * 16 + c15) * 16);
                    acc[mt][0] = __builtin_amdgcn_mfma_f32_16x16x32_bf16(a, wreg[ksl],      acc[mt][0], 0, 0, 0);
                    acc[mt][1] = __builtin_amdgcn_mfma_f32_16x16x32_bf16(a, wreg[20 + ksl], acc[mt][1], 0, 0, 0);
                }
        }
        // every wave dumps the OTHER row-half's partials to slot (nc,kh)
        {
            float* dp = (float*)(dumpbase + (nc * 2 + kh) * 2048);
            if (kh == 0) {
                *(f32x4*)(dp + (0 * 64 + lane) * 4) = acc[1][0];
                *(f32x4*)(dp + (1 * 64 + lane) * 4) = acc[1][1];
            } else {
                *(f32x4*)(dp + (0 * 64 + lane) * 4) = acc[0][0];
                *(f32x4*)(dp + (1 * 64 + lane) * 4) = acc[0][1];
            }
        }
        __syncthreads();
        // every wave: gates for its OWN row-half (mt = kh) — 4-way parallel
        {
            const float* dq = (const float*)(dumpbase + (nc * 2 + (1 - kh)) * 2048);
            f32x4 g0, g1;
            if (kh == 0) {
                g0 = acc[0][0] + *(const f32x4*)(dq + (0 * 64 + lane) * 4);
                g1 = acc[0][1] + *(const f32x4*)(dq + (1 * 64 + lane) * 4);
            } else {
                g0 = acc[1][0] + *(const f32x4*)(dq + (0 * 64 + lane) * 4);
                g1 = acc[1][1] + *(const f32x4*)(dq + (1 * 64 + lane) * 4);
            }
            bool low = (lane & 8) == 0;
            f32x4 av4;
#pragma unroll
            for (int r = 0; r < 4; ++r) {
                float fo0 = __shfl(g0[r], lane ^ 8);   // f gate from partner lane
                float fo1 = __shfl(g1[r], lane ^ 8);   // o gate from partner lane
                int rl = kh * 16 + q * 4 + r;          // local row 0..31 (wave-disjoint)
                float si = sigm(g0[r] + b_ii);
                float sf = sigm(fo0 + b_ff);
                float tg = tanhf(g1[r] + b_gg);
                float so = sigm(fo1 + b_oo);
                float cprev = auxf[rl * 16 + nc * 8 + hc];
                float cn = sf * cprev + si * tg;
                float hn = so * tanhf(cn);
                float av = low ? hn * attw_l : 0.f;
                av += __shfl_xor(av, 1); av += __shfl_xor(av, 2); av += __shfl_xor(av, 4);
                av4[r] = av;
                if (low) {
                    auxf[rl * 16 + nc * 8 + hc] = cn;
                    hscr[nc * 256 + rl * 8 + hc] = f2bf(hn);   // [ch=nc][row][8col]
                }
            }
            if (c15 == 0)
                *(f32x4*)(att_part + (size_t)(bid * 2 + nc) * 16384
                          + (size_t)tx * 32 + (kh * 16 + q * 4)) = av4;
        }
        __syncthreads();   // hscr complete; smem h image dead
        if (tid < 64) {    // block's 1KB region: 16 full-line WT stores + drain + post
            u32x4 v = *(const u32x4*)(hscr + tid * 8);
            store_16B_wt((char*)h_lstm
                         + (size_t)((dir * 2 + ((t + 1) & 1)) * 2 + rh) * 65536
                         + (size_t)(cg * 64 + tid) * 16, v);
            asm volatile("s_waitcnt vmcnt(0)" ::: "memory");
            if (tid == 0)
                __hip_atomic_store(flags + dir * 128 + rh * 64 + cg, (unsigned)(t + 1),
                                   __ATOMIC_RELAXED, __HIP_MEMORY_SCOPE_AGENT);
        }
    }

    // =============== attention finalize ===============
    flag_barrier(flags, 256, 256, 256 + bid, 2u);   // heavy: att_part cached-written
    {
        int i = tid & 127, half = tid >> 7;          // half = dir
        int item = bid * 128 + i;                    // 32768 = 512 t x 64 rows
        int tt = item >> 6, grow = item & 63;
        int rl = grow & 31, rh2 = grow >> 5;
        float s = 0.f;
        const float* p = att_part + (size_t)((half + rh2 * 2) * 2) * 16384
                         + (size_t)tt * 32 + rl;
        for (int cgi = 0; cgi < 64; ++cgi) {
            size_t off = (size_t)cgi * 8 * 16384;    // slot stride per cg = 8
            s += p[off] + p[off + 16384];            // nc = 0, 1
        }
        float* red = (float*)dumpbase;
        if (half) red[i] = s;
        __syncthreads();
        if (!half)
            out[BATCH * COUT + grow * SEQ + tt] = sigm(ATT_SIG_W * (s + red[i] + att_fc_b[0]));
    }
    flag_barrier(flags, 256, 256, 256 + bid, 3u);   // heavy: att out cached-written

    // =============== TAGM loop (256 blocks: rq = bid&3, cgT = bid>>2) ===============
    int rq = bid & 3, cgT = bid >> 2;
    int kq = wave;                                    // K-quarter 0..3
    bf16x8 wt[10];
    {
        const unsigned short* wp = Wtp + (size_t)(cgT * 4 + kq) * 5120;
#pragma unroll
        for (int f = 0; f < 10; ++f)
            wt[f] = *(const bf16x8*)(wp + f * 512 + lane * 8);
    }
    int colT = cgT * 16 + c15;
    float bbT = i2h_b[colT] + h2h_b[colT];
    for (int i = tid; i < 256; i += 256) auxf[i] = 0.f;   // h master [16][16]
    __syncthreads();
    const float* attd = out + BATCH * COUT;

    for (int t = 0; t < SEQ; ++t) {
        bf16x8 xa[8];
        if (kq == 0) {
            const unsigned short* xrow = xt + (size_t)t * BATCH * DIM;
#pragma unroll
            for (int ksl = 0; ksl < 8; ++ksl) {
                int row = rq * 16 + c15;
                xa[ksl] = *(const bf16x8*)(xrow + row * DIM + ksl * 32 + q * 8);
            }
        }
        if (t > 0) {
            for (;;) {
                bool ok = true;
                if (lane < 16)
                    ok = (__hip_atomic_load(flags + 512 + rq * 64 + wave * 16 + lane,
                                            __ATOMIC_RELAXED,
                                            __HIP_MEMORY_SCOPE_AGENT) >= (unsigned)t);
                if (__all(ok)) break;
                __builtin_amdgcn_s_sleep(1);
            }
        }
        __builtin_amdgcn_sched_barrier(0);
        {   // stage rq's 32KB h image: identity linear copy, 8 chunks/thread
            const char* hsrc = (const char*)h_tagm + (size_t)((t & 1) * 4 + rq) * 32768;
            char* lbase = smem + (size_t)wave * 8192 + (size_t)lane * 16;
#pragma unroll
            for (int i = 0; i < 8; ++i) {
                int s = wave * 512 + i * 64 + lane;
                GLOAD_LDS_COHERENT(hsrc + (size_t)s * 16, lbase + (size_t)i * 1024);
            }
        }
        f32x4 acc = {};
        if (kq == 0) {   // x-MFMAs overlap the in-flight stage
#pragma unroll
            for (int ksl = 0; ksl < 8; ++ksl)
                acc = __builtin_amdgcn_mfma_f32_16x16x32_bf16(xa[ksl], wt[ksl], acc, 0, 0, 0);
        }
        __syncthreads();
        if (kq == 0) {
#pragma unroll
            for (int ksl = 8; ksl < 10; ++ksl) {
                int kcol = ksl * 32 + q * 8 - 256;
                bf16x8 a = *(const bf16x8*)(smem + (size_t)(kcol >> 3) * 256
                                            + (size_t)c15 * 16);
                acc = __builtin_amdgcn_mfma_f32_16x16x32_bf16(a, wt[ksl], acc, 0, 0, 0);
            }
        } else {
#pragma unroll
            for (int ksl = 0; ksl < 10; ++ksl) {
                int kcol = kq * 320 + ksl * 32 + q * 8 - 256;
                bf16x8 a = *(const bf16x8*)(smem + (size_t)(kcol >> 3) * 256
                                            + (size_t)c15 * 16);
                acc = __builtin_amdgcn_mfma_f32_16x16x32_bf16(a, wt[ksl], acc, 0, 0, 0);
            }
        }
        *(f32x4*)(dumpbase + kq * 1024 + lane * 16) = acc;   // all waves dump
        __syncthreads();
        {   // wave kq gates rows kq*4..kq*4+3 (1 elem/lane) — 4-way parallel
            int rr = lane >> 4;
            int col = c15;
            int row = kq * 4 + rr;
            const float* db = (const float*)dumpbase;
            int e = (kq * 16 + col) * 4 + rr;
            float g = db[e] + db[256 + e] + db[512 + e] + db[768 + e] + bbT;
            float cand = g > 0.f ? g : 0.f;
            float a = attd[(rq * 16 + row) * SEQ + t];
            float hold = auxf[row * 16 + col];
            float hn = a * cand + (1.f - a) * hold;
            auxf[row * 16 + col] = hn;
            hscr[(col >> 3) * 128 + row * 8 + (col & 7)] = f2bf(hn);
        }
        __syncthreads();
        if (tid < 32) {   // block's 512B region: 8 full lines + drain + post
            u32x4 v = *(const u32x4*)(hscr + tid * 8);
            store_16B_wt((char*)h_tagm + (size_t)((((t + 1) & 1)) * 4 + rq) * 32768
                         + (size_t)(cgT * 32 + tid) * 16, v);
            asm volatile("s_waitcnt vmcnt(0)" ::: "memory");
            if (tid == 0)
                __hip_atomic_store(flags + 512 + rq * 64 + cgT, (unsigned)(t + 1),
                                   __ATOMIC_RELAXED, __HIP_MEMORY_SCOPE_AGENT);
        }
    }

    // dump final h (f32) for FC
    for (int i = tid; i < 256; i += 256) {
        int rl = i >> 4, cl = i & 15;
        h_f32[(size_t)(rq * 16 + rl) * HID + cgT * 16 + cl] = auxf[i];
    }
    flag_barrier(flags, 768, 256, 768 + bid, 1u);   // heavy: h_f32 cached-written
    if (bid >= 64) return;

    // =============== FC: out[b][c], block = batch row ===============
    {
        float* fcp = (float*)dumpbase;   // [2][128]
        int c = tid & 127, half = tid >> 7;
        const float* hrow = h_f32 + (size_t)bid * HID;
        float s = 0.f;
        for (int k = half * 512; k < half * 512 + 512; ++k)
            s += hrow[k] * fc_w[(size_t)k * COUT + c];
        fcp[half * 128 + c] = s;
        __syncthreads();
        if (tid < 128)
            out[bid * COUT + tid] = fcp[tid] + fcp[128 + tid] + fc_b[tid];
    }
}

extern "C" void kernel_launch(void* const* d_in, const int* in_sizes, int n_in,
                              void* d_out, int out_size, void* d_ws, size_t ws_size,
                              hipStream_t stream) {
    const float* x          = (const float*)d_in[0];
    const float* i2h_w      = (const float*)d_in[1];
    const float* i2h_b      = (const float*)d_in[2];
    const float* h2h_w      = (const float*)d_in[3];
    const float* h2h_b      = (const float*)d_in[4];
    const float* fc_w       = (const float*)d_in[5];
    const float* fc_b       = (const float*)d_in[6];
    const float* att_wi_fwd = (const float*)d_in[7];
    const float* att_wh_fwd = (const float*)d_in[8];
    const float* att_b_fwd  = (const float*)d_in[9];
    const float* att_wi_bwd = (const float*)d_in[10];
    const float* att_wh_bwd = (const float*)d_in[11];
    const float* att_b_bwd  = (const float*)d_in[12];
    const float* att_fc_w   = (const float*)d_in[13];
    const float* att_fc_b   = (const float*)d_in[14];
    float* out = (float*)d_out;

    char* ws = (char*)d_ws;
    // setup-phase (dead after packs)
    unsigned short* WfT = (unsigned short*)(ws + 0);          // 10485760
    unsigned short* WbT = (unsigned short*)(ws + 10485760);   // 10485760
    unsigned short* WtT = (unsigned short*)(ws + 20971520);   // 2621440 -> 23592960
    // packed fragment weights
    unsigned short* Wfp = (unsigned short*)(ws + 23592960);   // 10485760
    unsigned short* Wbp = (unsigned short*)(ws + 34078720);   // 10485760 -> 44564480
    unsigned short* Wtp = (unsigned short*)(ws + 17829888);   // 2621440 -> 20451328 (survives)
    // runtime region
    unsigned short* xtb    = (unsigned short*)(ws + 0);        // 16777216
    unsigned short* h_lstm = (unsigned short*)(ws + 16777216); // 524288
    unsigned short* h_tagm = (unsigned short*)(ws + 17301504); // 262144
    float*          h_f32  = (float*)(ws + 17563648);          // 262144
    unsigned*       flags  = (unsigned*)(ws + 17825792);       // 4096 -> 17829888
    // att_part ALIASES Wfp/Wbp (weights register-resident after epoch-1 barrier)
    float*          att_part = (float*)(ws + 23592960);        // 512*16384*4 = 33554432

    transpose_weights<<<20 * (NGATE / 64), 256, 0, stream>>>(att_wi_fwd, att_wh_fwd, WfT, NGATE);
    transpose_weights<<<20 * (NGATE / 64), 256, 0, stream>>>(att_wi_bwd, att_wh_bwd, WbT, NGATE);
    transpose_weights<<<20 * (HID / 64), 256, 0, stream>>>(i2h_w, h2h_w, WtT, HID);
    pack_lstm<<<256, 256, 0, stream>>>(WfT, Wfp);
    pack_lstm<<<256, 256, 0, stream>>>(WbT, Wbp);
    pack_tagm<<<256, 256, 0, stream>>>(WtT, Wtp);
    transpose_x<<<(SEQ * BATCH * DIM + 255) / 256, 256, 0, stream>>>(x, xtb);
    // zero recurrent state + flags every call
    (void)hipMemsetAsync(ws + 16777216, 0, 17829888 - 16777216, stream);

    // 96KB LDS: forces 1 block/CU
    static const int SMEM_BYTES = 98304;
    (void)hipFuncSetAttribute(reinterpret_cast<const void*>(tagm_fused),
                              hipFuncAttributeMaxDynamicSharedMemorySize, SMEM_BYTES);
    tagm_fused<<<256, 256, SMEM_BYTES, stream>>>(
        xtb, Wfp, Wbp, Wtp, att_b_fwd, att_b_bwd, att_fc_w, att_fc_b,
        i2h_b, h2h_b, fc_w, fc_b, h_lstm, h_tagm, h_f32, att_part, flags, out);
}